// Round 10
// baseline (343.822 us; speedup 1.0000x reference)
//
#include <hip/hip_runtime.h>
#include <math.h>

typedef unsigned short u16;
typedef __bf16 bf16x8 __attribute__((ext_vector_type(8)));
typedef float  f32x4  __attribute__((ext_vector_type(4)));

constexpr int B_  = 16384;   // batch
constexpr int DIN = 1024;    // input dim
constexpr int DH  = 2048;    // hidden dim
constexpr int DL  = 256;     // latent dim
constexpr int NE  = 8192;    // codebook entries

__device__ __forceinline__ u16 f2bf(float f) {     // RTNE float->bf16
    union { float f; unsigned u; } v; v.f = f;
    unsigned r = v.u + 0x7fffu + ((v.u >> 16) & 1u);
    return (u16)(r >> 16);
}
__device__ __forceinline__ float bf2f(u16 h) {
    union { unsigned u; float f; } v; v.u = ((unsigned)h) << 16;
    return v.f;
}

#define GLD16(gp, lp)                                                  \
    __builtin_amdgcn_global_load_lds(                                  \
        (__attribute__((address_space(1))) void*)(gp),                 \
        (__attribute__((address_space(3))) void*)(lp), 16, 0, 0)

#define SCHED0() __builtin_amdgcn_sched_barrier(0)
#define BARRIER() do { SCHED0(); __builtin_amdgcn_s_barrier(); SCHED0(); } while (0)
#define WAITV0() asm volatile("s_waitcnt vmcnt(0)" ::: "memory")
#define WAITV3() asm volatile("s_waitcnt vmcnt(3)" ::: "memory")
#define WAITV4() asm volatile("s_waitcnt vmcnt(4)" ::: "memory")

// ---------------------------------------------------------------------------
// cast fp32 -> bf16, 4 elts/thread (n % 1024 == 0)
// ---------------------------------------------------------------------------
__global__ __launch_bounds__(256)
void cast_bf16(const float* __restrict__ in, u16* __restrict__ out)
{
    const size_t i = ((size_t)blockIdx.x * 256 + threadIdx.x) * 4;
    float4 v = *(const float4*)(in + i);
    ushort4 o;
    o.x = f2bf(v.x); o.y = f2bf(v.y); o.z = f2bf(v.z); o.w = f2bf(v.w);
    *(ushort4*)(out + i) = o;
}

// ---------------------------------------------------------------------------
// transpose-cast: in [R][C] fp32 -> out [C][R] bf16.  32x32 LDS tile.
// ---------------------------------------------------------------------------
__global__ __launch_bounds__(256)
void transpose_cast(const float* __restrict__ in, u16* __restrict__ out,
                    int R, int C)
{
    __shared__ float t[32][33];
    const int tx = threadIdx.x & 31, ty = threadIdx.x >> 5;
    const long bx = blockIdx.x;   // C/32
    const long by = blockIdx.y;   // R/32
#pragma unroll
    for (int p = 0; p < 4; ++p)
        t[ty + p * 8][tx] = in[(by * 32 + ty + p * 8) * (long)C + bx * 32 + tx];
    __syncthreads();
#pragma unroll
    for (int p = 0; p < 4; ++p)
        out[(bx * 32 + ty + p * 8) * (long)R + by * 32 + tx] = f2bf(t[tx][ty + p * 8]);
}

// ---------------------------------------------------------------------------
// cn2[k] = 0.5 * ||codebook[k]||^2 (fp32). One wave per code.
// ---------------------------------------------------------------------------
__global__ __launch_bounds__(256)
void cn2_kernel(const float* __restrict__ cb, float* __restrict__ cn2)
{
    const int code = (blockIdx.x * 256 + threadIdx.x) >> 6;
    const int lane = threadIdx.x & 63;
    float4 v = *(const float4*)(cb + (long)code * DL + lane * 4);
    float s = fmaf(v.x, v.x, fmaf(v.y, v.y, fmaf(v.z, v.z, v.w * v.w)));
#pragma unroll
    for (int off = 32; off; off >>= 1) s += __shfl_down(s, off);
    if (lane == 0) cn2[code] = 0.5f * s;
}

// ---------------------------------------------------------------------------
// 256x256 bf16 MFMA GEMM: BK=32, 512 threads = 8 waves (2M x 4N), wave tile
// 128x64 -> acc[8][4], 32 MFMA vs 12 ds_read per step (ratio 0.375, -25%
// LDS traffic/FLOP vs the 64x64 wave tile). Same proven r8 sync skeleton:
// 3 LDS buffers (96KB), depth-2 prefetch, counted vmcnt(4) + one raw
// s_barrier per K-step, both-sides XOR swizzle (conflict-free, r8-verified).
// Accumulation chain per output element unchanged -> bitwise-same C.
// Requires M%256==0, N%256==0, nwg%8==0.
// EPI: 1 = bias+relu->bf16, 2 = bias+sigmoid->f32
// ---------------------------------------------------------------------------
template <int EPI>
__global__ __launch_bounds__(512, 2)
void gemm_256_bf16(const u16* __restrict__ A, const u16* __restrict__ Bt,
                   const float* __restrict__ bias, void* __restrict__ Cout,
                   int M, int N, int K)
{
    __shared__ __align__(16) u16 As[3 * 8192];   // 3 x 16 KB (256r x 32k)
    __shared__ __align__(16) u16 Bs[3 * 8192];

    const int tid = threadIdx.x;
    const int w = tid >> 6, l = tid & 63;
    const int wm = w >> 2, wn = w & 3;           // 2M x 4N wave grid

    const int nbx   = N >> 8;
    const int nwg   = (M >> 8) * nbx;
    const int chunk = nwg >> 3;
    const int wg    = ((int)blockIdx.x & 7) * chunk + ((int)blockIdx.x >> 3);
    const long by   = wg / nbx;
    const long bx   = wg % nbx;

    const int lr  = l >> 2;                      // row within 16-row segment
    const int lsw = (l & 3) ^ ((l >> 3) & 3);    // swizzled source chunk
    const int lg  = l >> 4, lm = l & 15;         // frag k-group / row index
    const int sx  = (lm >> 1) & 3;               // read-side xor key

    const u16* Abase = A  + (size_t)(by * 256) * K;
    const u16* Bbase = Bt + (size_t)(bx * 256) * K;

    f32x4 acc[8][4] = {};

    auto stage = [&](int k0, int b) {
        u16* dA = As + b * 8192;
        u16* dB = Bs + b * 8192;
#pragma unroll
        for (int i = 0; i < 2; ++i) {
            const int seg = w * 2 + i;           // 0..15 -> 16 rows each
            GLD16(Abase + (size_t)(seg * 16 + lr) * K + k0 + lsw * 8,
                  dA + seg * 512);
            GLD16(Bbase + (size_t)(seg * 16 + lr) * K + k0 + lsw * 8,
                  dB + seg * 512);
        }
    };

    const int NT = K >> 5;
    stage(0, 0);
    stage(32, 1);

    int cur = 0, pre = 2;
    for (int t = 0; t < NT; ++t) {
        if (t + 1 < NT) { WAITV4(); } else { WAITV0(); }
        BARRIER();
        if (t + 2 < NT) stage((t + 2) << 5, pre);

        const u16* as = As + cur * 8192;
        const u16* bs = Bs + cur * 8192;
        bf16x8 af[8], bfr[4];
#pragma unroll
        for (int m = 0; m < 8; ++m) {
            const int R = wm * 128 + m * 16 + lm;
            af[m] = *(const bf16x8*)&as[R * 32 + ((lg ^ sx) * 8)];
        }
#pragma unroll
        for (int n = 0; n < 4; ++n) {
            const int R = wn * 64 + n * 16 + lm;
            bfr[n] = *(const bf16x8*)&bs[R * 32 + ((lg ^ sx) * 8)];
        }
#pragma unroll
        for (int m = 0; m < 8; ++m)
#pragma unroll
            for (int n = 0; n < 4; ++n)
                acc[m][n] = __builtin_amdgcn_mfma_f32_16x16x32_bf16(
                    af[m], bfr[n], acc[m][n], 0, 0, 0);

        cur = (cur == 2) ? 0 : cur + 1;
        pre = (pre == 2) ? 0 : pre + 1;
    }

    // epilogue: row = by*256+wm*128+m*16+lg*4+j, col = bx*256+wn*64+n*16+lm
#pragma unroll
    for (int n = 0; n < 4; ++n) {
        const long col = bx * 256 + wn * 64 + n * 16 + lm;
        const float bb = bias[col];
#pragma unroll
        for (int m = 0; m < 8; ++m) {
#pragma unroll
            for (int j = 0; j < 4; ++j) {
                const long row = by * 256 + wm * 128 + m * 16 + lg * 4 + j;
                float e = acc[m][n][j] + bb;
                if (EPI == 1) e = fmaxf(e, 0.f);
                if (EPI == 2) {
                    e = 1.f / (1.f + expf(-e));
                    ((float*)Cout)[row * (long)N + col] = e;
                } else {
                    ((u16*)Cout)[row * (long)N + col] = f2bf(e);
                }
            }
        }
    }
}

// ---------------------------------------------------------------------------
// BIG bf16 MFMA GEMM: BM=256, BN=128 (r8 version) — used for decoder GEMMs.
// EPI: 1 = bias+relu->bf16, 2 = bias+sigmoid->f32
// ---------------------------------------------------------------------------
template <int EPI>
__global__ __launch_bounds__(512, 4)
void gemm_big_bf16(const u16* __restrict__ A, const u16* __restrict__ Bt,
                   const float* __restrict__ bias, void* __restrict__ Cout,
                   int M, int N, int K)
{
    __shared__ __align__(16) u16 As[3 * 8192];   // 3 x 16 KB (256 rows x 32)
    __shared__ __align__(16) u16 Bs[3 * 4096];   // 3 x  8 KB (128 rows x 32)

    const int tid = threadIdx.x;
    const int w = tid >> 6, l = tid & 63;
    const int wm = w >> 1, wn = w & 1;

    const int nbx   = N >> 7;
    const int nwg   = (M >> 8) * nbx;
    const int chunk = nwg >> 3;
    const int wg    = ((int)blockIdx.x & 7) * chunk + ((int)blockIdx.x >> 3);
    const long by   = wg / nbx;
    const long bx   = wg % nbx;

    const int lr  = l >> 2;
    const int lsw = (l & 3) ^ ((l >> 3) & 3);
    const int lg  = l >> 4, lm = l & 15;
    const int sx  = (lm >> 1) & 3;

    const u16* Abase = A  + (size_t)(by * 256) * K;
    const u16* Bbase = Bt + (size_t)(bx * 128) * K;

    f32x4 acc[4][4] = {};

    auto stage = [&](int k0, int b) {
        u16* dA = As + b * 8192;
        u16* dB = Bs + b * 4096;
#pragma unroll
        for (int i = 0; i < 2; ++i) {
            const int seg = w * 2 + i;
            GLD16(Abase + (size_t)(seg * 16 + lr) * K + k0 + lsw * 8,
                  dA + seg * 512);
        }
        GLD16(Bbase + (size_t)(w * 16 + lr) * K + k0 + lsw * 8,
              dB + w * 512);
    };

    const int NT = K >> 5;
    stage(0, 0);
    stage(32, 1);

    int cur = 0, pre = 2;
    for (int t = 0; t < NT; ++t) {
        if (t + 1 < NT) { WAITV3(); } else { WAITV0(); }
        BARRIER();
        if (t + 2 < NT) stage((t + 2) << 5, pre);

        const u16* as = As + cur * 8192;
        const u16* bs = Bs + cur * 4096;
        bf16x8 af[4], bfr[4];
#pragma unroll
        for (int m = 0; m < 4; ++m) {
            const int R = wm * 64 + m * 16 + lm;
            af[m] = *(const bf16x8*)&as[R * 32 + ((lg ^ sx) * 8)];
        }
#pragma unroll
        for (int n = 0; n < 4; ++n) {
            const int R = wn * 64 + n * 16 + lm;
            bfr[n] = *(const bf16x8*)&bs[R * 32 + ((lg ^ sx) * 8)];
        }
#pragma unroll
        for (int m = 0; m < 4; ++m)
#pragma unroll
            for (int n = 0; n < 4; ++n)
                acc[m][n] = __builtin_amdgcn_mfma_f32_16x16x32_bf16(
                    af[m], bfr[n], acc[m][n], 0, 0, 0);

        cur = (cur == 2) ? 0 : cur + 1;
        pre = (pre == 2) ? 0 : pre + 1;
    }

#pragma unroll
    for (int n = 0; n < 4; ++n) {
        const long col = bx * 128 + wn * 64 + n * 16 + lm;
        const float bb = bias[col];
#pragma unroll
        for (int m = 0; m < 4; ++m) {
#pragma unroll
            for (int j = 0; j < 4; ++j) {
                const long row = by * 256 + wm * 64 + m * 16 + lg * 4 + j;
                float e = acc[m][n][j] + bb;
                if (EPI == 1) e = fmaxf(e, 0.f);
                if (EPI == 2) {
                    e = 1.f / (1.f + expf(-e));
                    ((float*)Cout)[row * (long)N + col] = e;
                } else {
                    ((u16*)Cout)[row * (long)N + col] = f2bf(e);
                }
            }
        }
    }
}

// ---------------------------------------------------------------------------
// 128^2 bf16 MFMA GEMM for GEMM2 (N=256). T4 counted-vmcnt, swizzled.
// EPI: 0 = bias->bf16
// ---------------------------------------------------------------------------
template <int EPI>
__global__ __launch_bounds__(256)
void gemm_bt_bf16(const u16* __restrict__ A, const u16* __restrict__ Bt,
                  const float* __restrict__ bias, void* __restrict__ Cout,
                  int M, int N, int K)
{
    __shared__ __align__(16) u16 As[3 * 4096];
    __shared__ __align__(16) u16 Bs[3 * 4096];

    const int tid = threadIdx.x;
    const int w = tid >> 6, l = tid & 63;
    const int wr = w >> 1, wc = w & 1;

    const int nbx   = N >> 7;
    const int nwg   = (M >> 7) * nbx;
    const int chunk = nwg >> 3;
    const int wg    = ((int)blockIdx.x & 7) * chunk + ((int)blockIdx.x >> 3);
    const long by   = wg / nbx;
    const long bx   = wg % nbx;

    const int lr  = l >> 2;
    const int lsw = (l & 3) ^ ((l >> 3) & 3);
    const int lg  = l >> 4, lm = l & 15;
    const int sx  = (lm >> 1) & 3;

    const u16* Abase = A  + (size_t)(by * 128) * K;
    const u16* Bbase = Bt + (size_t)(bx * 128) * K;

    f32x4 acc[4][4] = {};

    auto stage = [&](int k0, int b) {
        u16* dA = As + b * 4096;
        u16* dB = Bs + b * 4096;
#pragma unroll
        for (int i = 0; i < 2; ++i) {
            const int seg = w * 2 + i;
            GLD16(Abase + (size_t)(seg * 16 + lr) * K + k0 + lsw * 8, dA + seg * 512);
            GLD16(Bbase + (size_t)(seg * 16 + lr) * K + k0 + lsw * 8, dB + seg * 512);
        }
    };

    const int NT = K >> 5;
    stage(0, 0);
    stage(32, 1);

    int cur = 0, pre = 2;
    for (int t = 0; t < NT; ++t) {
        if (t + 1 < NT) { WAITV4(); } else { WAITV0(); }
        BARRIER();
        if (t + 2 < NT) stage((t + 2) << 5, pre);

        const u16* as = As + cur * 4096;
        const u16* bs = Bs + cur * 4096;
        bf16x8 af[4], bfr[4];
#pragma unroll
        for (int m = 0; m < 4; ++m)
            af[m] = *(const bf16x8*)&as[(wr * 64 + m * 16 + lm) * 32 + ((lg ^ sx) * 8)];
#pragma unroll
        for (int n = 0; n < 4; ++n)
            bfr[n] = *(const bf16x8*)&bs[(wc * 64 + n * 16 + lm) * 32 + ((lg ^ sx) * 8)];
#pragma unroll
        for (int m = 0; m < 4; ++m)
#pragma unroll
            for (int n = 0; n < 4; ++n)
                acc[m][n] = __builtin_amdgcn_mfma_f32_16x16x32_bf16(
                    af[m], bfr[n], acc[m][n], 0, 0, 0);

        cur = (cur == 2) ? 0 : cur + 1;
        pre = (pre == 2) ? 0 : pre + 1;
    }

#pragma unroll
    for (int n = 0; n < 4; ++n) {
        const long col = bx * 128 + wc * 64 + n * 16 + lm;
        const float bb = bias[col];
#pragma unroll
        for (int m = 0; m < 4; ++m) {
#pragma unroll
            for (int j = 0; j < 4; ++j) {
                const long row = by * 128 + wr * 64 + m * 16 + lg * 4 + j;
                float e = acc[m][n][j] + bb;
                if (EPI == 1) e = fmaxf(e, 0.f);
                if (EPI == 2) {
                    e = 1.f / (1.f + expf(-e));
                    ((float*)Cout)[row * (long)N + col] = e;
                } else {
                    ((u16*)Cout)[row * (long)N + col] = f2bf(e);
                }
            }
        }
    }
}

// ---------------------------------------------------------------------------
// VQ phase 1 v2: register-resident A, LDS-streamed codebook (unchanged).
// ---------------------------------------------------------------------------
__global__ __launch_bounds__(256, 2)
void vq_score2(const u16* __restrict__ z, const u16* __restrict__ cbt,
               const float* __restrict__ cn2,
               float* __restrict__ val8, int* __restrict__ idx8)
{
    __shared__ __align__(16) u16 lds[32768];

    const int tid = threadIdx.x;
    const int w = tid >> 6, l = tid & 63;
    const int rq = blockIdx.x >> 3;
    const int q  = blockIdx.x & 7;

    const int st_row8 = tid >> 5;
    const int st_s    = (tid & 31) ^ st_row8;
    const int lg = l >> 4, lm = l & 15;
    const int swz_x = l & 7;

    bf16x8 af[4][8];
    const long zbase_row = (long)rq * 256;
#pragma unroll
    for (int h = 0; h < 2; ++h) {
#pragma unroll
        for (int i = 0; i < 16; ++i) {
            const int row = i * 8 + st_row8;
            const u16* g = z + (zbase_row + h * 128 + row) * DL + st_s * 8;
            GLD16(g, lds + ((size_t)i * 256 + w * 64) * 8);
        }
        __syncthreads();
        if ((w >> 1) == h) {
            const int lrow0 = (w & 1) * 64;
#pragma unroll
            for (int m = 0; m < 4; ++m) {
                const int lrow = lrow0 + m * 16 + lm;
#pragma unroll
                for (int kg = 0; kg < 8; ++kg) {
                    const int s = (kg * 4 + lg) ^ swz_x;
                    af[m][kg] = *(const bf16x8*)&lds[lrow * 256 + s * 8];
                }
            }
        }
        __syncthreads();
    }

    const int code00 = q * (NE / 8);

    float bestv[16];
    int   besti[16];
#pragma unroll
    for (int k = 0; k < 16; ++k) { bestv[k] = 1e30f; besti[k] = 0; }

    auto stage_tile = [&](int t) {
        const int b = t & 1;
#pragma unroll
        for (int i = 0; i < 8; ++i) {
            const int c = i * 8 + st_row8;
            const u16* g = cbt + (size_t)(code00 + t * 64 + c) * DL + st_s * 8;
            GLD16(g, lds + ((size_t)b * 16384 + ((size_t)i * 256 + w * 64) * 8));
        }
    };

    stage_tile(0);
    __syncthreads();

    for (int t = 0; t < 16; ++t) {
        if (t < 15) stage_tile(t + 1);
        const u16* buf = lds + (size_t)(t & 1) * 16384;

#pragma unroll
        for (int n = 0; n < 4; ++n) {
            const int code_g = code00 + t * 64 + n * 16 + lm;
            const float cn2v = cn2[code_g];
            bf16x8 bfr[8];
#pragma unroll
            for (int kg = 0; kg < 8; ++kg) {
                const int lrow = n * 16 + lm;
                const int s = (kg * 4 + lg) ^ swz_x;
                bfr[kg] = *(const bf16x8*)&buf[lrow * 256 + s * 8];
            }
            f32x4 acc[4] = {};
#pragma unroll
            for (int kg = 0; kg < 8; ++kg)
#pragma unroll
                for (int m = 0; m < 4; ++m)
                    acc[m] = __builtin_amdgcn_mfma_f32_16x16x32_bf16(
                        af[m][kg], bfr[kg], acc[m], 0, 0, 0);
#pragma unroll
            for (int m = 0; m < 4; ++m)
#pragma unroll
                for (int j = 0; j < 4; ++j) {
                    const float s = cn2v - acc[m][j];
                    const int k16 = m * 4 + j;
                    if (s < bestv[k16]) { bestv[k16] = s; besti[k16] = code_g; }
                }
        }
        __syncthreads();
    }

#pragma unroll
    for (int off = 1; off < 16; off <<= 1) {
#pragma unroll
        for (int k = 0; k < 16; ++k) {
            const float ov = __shfl_xor(bestv[k], off);
            const int   oi = __shfl_xor(besti[k], off);
            if (ov < bestv[k] || (ov == bestv[k] && oi < besti[k])) {
                bestv[k] = ov; besti[k] = oi;
            }
        }
    }
    if (lm == 0) {
#pragma unroll
        for (int m = 0; m < 4; ++m)
#pragma unroll
            for (int j = 0; j < 4; ++j) {
                const long row = zbase_row + w * 64 + m * 16 + lg * 4 + j;
                val8[(size_t)q * B_ + row] = bestv[m * 4 + j];
                idx8[(size_t)q * B_ + row] = besti[m * 4 + j];
            }
    }
}

// ---------------------------------------------------------------------------
// VQ phase 2: per row pick best of 8 candidates (tie-break lowest idx),
// write final index, accumulate loss partial.
// ---------------------------------------------------------------------------
__global__ __launch_bounds__(256)
void vq_select2(const float* __restrict__ val8, const int* __restrict__ idx8,
                const u16* __restrict__ z, const float* __restrict__ cb,
                int* __restrict__ idxf, float* __restrict__ partial)
{
    __shared__ int   s_idx[256];
    __shared__ float s_red[4];
    const int tid = threadIdx.x;
    const long row = (long)blockIdx.x * 256 + tid;

    float bv = val8[row];
    int   bi = idx8[row];
#pragma unroll
    for (int qq = 1; qq < 8; ++qq) {
        const float v = val8[(size_t)qq * B_ + row];
        const int   i = idx8[(size_t)qq * B_ + row];
        if (v < bv || (v == bv && i < bi)) { bv = v; bi = i; }
    }
    s_idx[tid] = bi;
    idxf[row]  = bi;
    __syncthreads();

    float ls = 0.f;
    const int sub = tid & 7;
#pragma unroll
    for (int pass = 0; pass < 8; ++pass) {
        const int rl = pass * 32 + (tid >> 3);
        const int gi = s_idx[rl];
        const long rg = (long)blockIdx.x * 256 + rl;
#pragma unroll
        for (int tt = 0; tt < 8; ++tt) {
            const int d = sub * 4 + tt * 32;
            float4 c4 = *(const float4*)(cb + (long)gi * DL + d);
            ushort4 zu = *(const ushort4*)(z + rg * DL + d);
            const float dx = c4.x - bf2f(zu.x), dy = c4.y - bf2f(zu.y);
            const float dz = c4.z - bf2f(zu.z), dw = c4.w - bf2f(zu.w);
            ls += dx * dx + dy * dy + dz * dz + dw * dw;
        }
    }
#pragma unroll
    for (int off = 32; off; off >>= 1) ls += __shfl_down(ls, off);
    if ((tid & 63) == 0) s_red[tid >> 6] = ls;
    __syncthreads();
    if (tid == 0)
        partial[blockIdx.x] = s_red[0] + s_red[1] + s_red[2] + s_red[3];
}

// ---------------------------------------------------------------------------
// loss = 1.25 * sum(partial[64]) / (B_*DL)
// ---------------------------------------------------------------------------
__global__ __launch_bounds__(256)
void loss_finalize(const float* __restrict__ partial, float* __restrict__ out)
{
    __shared__ float s_red[4];
    const int tid = threadIdx.x;
    float s = (tid < 64) ? partial[tid] : 0.f;
#pragma unroll
    for (int off = 32; off; off >>= 1) s += __shfl_down(s, off);
    if ((tid & 63) == 0) s_red[tid >> 6] = s;
    __syncthreads();
    if (tid == 0)
        out[0] = 1.25f * (s_red[0] + s_red[1] + s_red[2] + s_red[3])
                 / (float)((long)B_ * DL);
}

// ---------------------------------------------------------------------------
// gather: out[row] = Xcode[idxf[row]]  (1024 f32/row; one wave per row).
// ---------------------------------------------------------------------------
__global__ __launch_bounds__(256)
void gather_rows(const float* __restrict__ Xcode, const int* __restrict__ idxf,
                 float* __restrict__ out)
{
    const int tid  = threadIdx.x;
    const int lane = tid & 63;
    const long row = (long)blockIdx.x * 4 + (tid >> 6);
    const long gi  = idxf[row];
    const float* src = Xcode + gi * DIN;
    float*       dst = out + row * DIN;
#pragma unroll
    for (int t = 0; t < 4; ++t) {
        const int d = lane * 4 + t * 256;
        *(float4*)(dst + d) = *(const float4*)(src + d);
    }
}

// ---------------------------------------------------------------------------
extern "C" void kernel_launch(void* const* d_in, const int* in_sizes, int n_in,
                              void* d_out, int out_size, void* d_ws, size_t ws_size,
                              hipStream_t stream)
{
    const float* x   = (const float*)d_in[0];
    const float* ew1 = (const float*)d_in[1];
    const float* eb1 = (const float*)d_in[2];
    const float* ew2 = (const float*)d_in[3];
    const float* eb2 = (const float*)d_in[4];
    const float* cbk = (const float*)d_in[5];
    const float* dw1 = (const float*)d_in[6];
    const float* db1 = (const float*)d_in[7];
    const float* dw2 = (const float*)d_in[8];
    const float* db2 = (const float*)d_in[9];
    float* out = (float*)d_out;

    char* p = (char*)d_ws;
    auto alloc = [&](size_t bytes) {
        char* r = p; p += (bytes + 255) & ~(size_t)255; return r;
    };
    u16*   x_bf  = (u16*)alloc((size_t)B_ * DIN * 2);
    u16*   h_bf  = (u16*)alloc((size_t)B_ * DH * 2);   // encoder h; then Hcode
    u16*   z_bf  = (u16*)alloc((size_t)B_ * DL * 2);
    u16*   cb_bf = (u16*)alloc((size_t)NE * DL * 2);
    u16*   w1t   = (u16*)alloc((size_t)DH * DIN * 2);  // [N][K] bf16
    u16*   w2t   = (u16*)alloc((size_t)DL * DH * 2);
    u16*   wd1t  = (u16*)alloc((size_t)DH * DL * 2);
    u16*   wd2t  = (u16*)alloc((size_t)DIN * DH * 2);
    float* Xcode = (float*)alloc((size_t)NE * DIN * 4);   // per-code recon
    float* cn2   = (float*)alloc((size_t)NE * 4);
    float* val8  = (float*)alloc((size_t)8 * B_ * 4);
    int*   idx8  = (int*)alloc((size_t)8 * B_ * 4);
    int*   idxf  = (int*)alloc((size_t)B_ * 4);
    float* part  = (float*)alloc(64 * 4);

    // casts / transposes (weights -> [N][K] bf16)
    cast_bf16<<<(size_t)B_ * DIN / 1024, 256, 0, stream>>>(x, x_bf);
    cast_bf16<<<(size_t)NE * DL / 1024, 256, 0, stream>>>(cbk, cb_bf);
    transpose_cast<<<dim3(DH / 32, DIN / 32), 256, 0, stream>>>(ew1, w1t, DIN, DH);
    transpose_cast<<<dim3(DL / 32, DH / 32), 256, 0, stream>>>(ew2, w2t, DH, DL);
    transpose_cast<<<dim3(DH / 32, DL / 32), 256, 0, stream>>>(dw1, wd1t, DL, DH);
    transpose_cast<<<dim3(DIN / 32, DH / 32), 256, 0, stream>>>(dw2, wd2t, DH, DIN);
    cn2_kernel<<<NE / 4, 256, 0, stream>>>(cbk, cn2);

    // encoder: gemm1 on the new 256x256 kernel
    gemm_256_bf16<1><<<(B_ / 256) * (DH / 256), 512, 0, stream>>>(
        x_bf, w1t, eb1, h_bf, B_, DH, DIN);
    gemm_bt_bf16<0><<<(B_ / 128) * (DL / 128), 256, 0, stream>>>(
        h_bf, w2t, eb2, z_bf, B_, DL, DH);

    // vector quantizer -> final index per row + loss
    vq_score2<<<512, 256, 0, stream>>>(z_bf, cb_bf, cn2, val8, idx8);
    vq_select2<<<B_ / 256, 256, 0, stream>>>(val8, idx8, z_bf, cbk, idxf, part);
    loss_finalize<<<1, 256, 0, stream>>>(part, out + (size_t)B_ * DIN);

    // decoder per CODE (8192 rows), then gather rows by index.
    gemm_big_bf16<1><<<(NE / 256) * (DH / 128), 512, 0, stream>>>(
        cb_bf, wd1t, db1, h_bf, NE, DH, DL);
    gemm_big_bf16<2><<<(NE / 256) * (DIN / 128), 512, 0, stream>>>(
        h_bf, wd2t, db2, Xcode, NE, DIN, DH);
    gather_rows<<<B_ / 4, 256, 0, stream>>>(Xcode, idxf, out);
}

// Round 11
// 329.995 us; speedup vs baseline: 1.0419x; 1.0419x over previous
//
#include <hip/hip_runtime.h>
#include <math.h>

typedef unsigned short u16;
typedef __bf16 bf16x8 __attribute__((ext_vector_type(8)));
typedef float  f32x4  __attribute__((ext_vector_type(4)));

constexpr int B_  = 16384;   // batch
constexpr int DIN = 1024;    // input dim
constexpr int DH  = 2048;    // hidden dim
constexpr int DL  = 256;     // latent dim
constexpr int NE  = 8192;    // codebook entries

__device__ __forceinline__ u16 f2bf(float f) {     // RTNE float->bf16
    union { float f; unsigned u; } v; v.f = f;
    unsigned r = v.u + 0x7fffu + ((v.u >> 16) & 1u);
    return (u16)(r >> 16);
}
__device__ __forceinline__ float bf2f(u16 h) {
    union { unsigned u; float f; } v; v.u = ((unsigned)h) << 16;
    return v.f;
}

#define GLD16(gp, lp)                                                  \
    __builtin_amdgcn_global_load_lds(                                  \
        (__attribute__((address_space(1))) void*)(gp),                 \
        (__attribute__((address_space(3))) void*)(lp), 16, 0, 0)

#define SCHED0() __builtin_amdgcn_sched_barrier(0)
#define BARRIER() do { SCHED0(); __builtin_amdgcn_s_barrier(); SCHED0(); } while (0)
#define WAITV0() asm volatile("s_waitcnt vmcnt(0)" ::: "memory")
#define WAITV3() asm volatile("s_waitcnt vmcnt(3)" ::: "memory")
#define WAITV4() asm volatile("s_waitcnt vmcnt(4)" ::: "memory")
#define WAITV6() asm volatile("s_waitcnt vmcnt(6)" ::: "memory")
#define WAITLG0() do { asm volatile("s_waitcnt lgkmcnt(0)" ::: "memory"); SCHED0(); } while (0)

// ---------------------------------------------------------------------------
// cast fp32 -> bf16, 4 elts/thread (n % 1024 == 0)
// ---------------------------------------------------------------------------
__global__ __launch_bounds__(256)
void cast_bf16(const float* __restrict__ in, u16* __restrict__ out)
{
    const size_t i = ((size_t)blockIdx.x * 256 + threadIdx.x) * 4;
    float4 v = *(const float4*)(in + i);
    ushort4 o;
    o.x = f2bf(v.x); o.y = f2bf(v.y); o.z = f2bf(v.z); o.w = f2bf(v.w);
    *(ushort4*)(out + i) = o;
}

// ---------------------------------------------------------------------------
// transpose-cast: in [R][C] fp32 -> out [C][R] bf16.  32x32 LDS tile.
// ---------------------------------------------------------------------------
__global__ __launch_bounds__(256)
void transpose_cast(const float* __restrict__ in, u16* __restrict__ out,
                    int R, int C)
{
    __shared__ float t[32][33];
    const int tx = threadIdx.x & 31, ty = threadIdx.x >> 5;
    const long bx = blockIdx.x;   // C/32
    const long by = blockIdx.y;   // R/32
#pragma unroll
    for (int p = 0; p < 4; ++p)
        t[ty + p * 8][tx] = in[(by * 32 + ty + p * 8) * (long)C + bx * 32 + tx];
    __syncthreads();
#pragma unroll
    for (int p = 0; p < 4; ++p)
        out[(bx * 32 + ty + p * 8) * (long)R + by * 32 + tx] = f2bf(t[tx][ty + p * 8]);
}

// ---------------------------------------------------------------------------
// cn2[k] = 0.5 * ||codebook[k]||^2 (fp32). One wave per code.
// ---------------------------------------------------------------------------
__global__ __launch_bounds__(256)
void cn2_kernel(const float* __restrict__ cb, float* __restrict__ cn2)
{
    const int code = (blockIdx.x * 256 + threadIdx.x) >> 6;
    const int lane = threadIdx.x & 63;
    float4 v = *(const float4*)(cb + (long)code * DL + lane * 4);
    float s = fmaf(v.x, v.x, fmaf(v.y, v.y, fmaf(v.z, v.z, v.w * v.w)));
#pragma unroll
    for (int off = 32; off; off >>= 1) s += __shfl_down(s, off);
    if (lane == 0) cn2[code] = 0.5f * s;
}

// ---------------------------------------------------------------------------
// 8-phase bf16 MFMA GEMM (m201-style schedule on the proven 256x128 tile):
// BK=32, 512 threads = 8 waves (4M x 2N), wave tile 64x64.
// Per phase t: { ds_read frags(t) | issue stage(t+3) -> barrier ->
//   lgkmcnt(0) -> setprio(1) 16 MFMA setprio(0) -> counted vmcnt ->
//   barrier }. 4 LDS buffers (96KB, 1 block/CU -- the per-phase pipeline
// replaces inter-block overlap, m201 config). Prefetch depth 3; steady
// vmcnt(6) = 3 loads/stage x 2 stages allowed in flight; tail 6->3->0.
// Hazards: reads of buf[t] ordered behind stage(t) completion by each
// wave's end-of-phase-(t-1) counted wait + barrier#2; stage(t+3) targets
// buf[t-1], whose readers passed lgkmcnt(0) before barrier#2(t-1). All
// barriers sched_barrier(0)-bracketed (rule #18/#21 discipline).
// Math chain identical to r8/r9 kernels (same swizzle, same frags, same
// t-ascending MFMA) -> bitwise-same C. T1 XCD remap (nwg % 8 == 0).
// EPI: 1 = bias+relu->bf16, 2 = bias+sigmoid->f32
// ---------------------------------------------------------------------------
template <int EPI>
__global__ __launch_bounds__(512, 2)
void gemm_8ph_bf16(const u16* __restrict__ A, const u16* __restrict__ Bt,
                   const float* __restrict__ bias, void* __restrict__ Cout,
                   int M, int N, int K)
{
    __shared__ __align__(16) u16 As[4 * 8192];   // 4 x 16 KB (256 rows x 32)
    __shared__ __align__(16) u16 Bs[4 * 4096];   // 4 x  8 KB (128 rows x 32)

    const int tid = threadIdx.x;
    const int w = tid >> 6, l = tid & 63;
    const int wm = w >> 1, wn = w & 1;

    const int nbx   = N >> 7;
    const int nwg   = (M >> 8) * nbx;
    const int chunk = nwg >> 3;
    const int wg    = ((int)blockIdx.x & 7) * chunk + ((int)blockIdx.x >> 3);
    const long by   = wg / nbx;
    const long bx   = wg % nbx;

    const int lr  = l >> 2;                      // row within 16-row segment
    const int lsw = (l & 3) ^ ((l >> 3) & 3);    // swizzled source chunk
    const int lg  = l >> 4, lm = l & 15;         // frag k-group / row index
    const int sx  = (lm >> 1) & 3;               // read-side xor key

    const u16* Abase = A  + (size_t)(by * 256) * K;
    const u16* Bbase = Bt + (size_t)(bx * 128) * K;

    f32x4 acc[4][4] = {};

    auto stage = [&](int t) {
        const int b  = t & 3;
        const int k0 = t << 5;
        u16* dA = As + b * 8192;
        u16* dB = Bs + b * 4096;
#pragma unroll
        for (int i = 0; i < 2; ++i) {
            const int seg = w * 2 + i;           // 0..15 -> 16 rows each
            GLD16(Abase + (size_t)(seg * 16 + lr) * K + k0 + lsw * 8,
                  dA + seg * 512);
        }
        GLD16(Bbase + (size_t)(w * 16 + lr) * K + k0 + lsw * 8,
              dB + w * 512);
    };

    const int NT = K >> 5;                       // >= 8 for all our shapes
    stage(0); stage(1); stage(2);                // 9 loads in flight
    WAITV6();                                    // stage(0) landed (own)
    BARRIER();                                   // ... and globally

    for (int t = 0; t < NT; ++t) {
        // ds_read this phase's fragments (consumed after lgkmcnt below)
        const u16* as = As + (t & 3) * 8192;
        const u16* bs = Bs + (t & 3) * 4096;
        bf16x8 af[4], bfr[4];
#pragma unroll
        for (int m = 0; m < 4; ++m) {
            const int R = wm * 64 + m * 16 + lm;
            af[m] = *(const bf16x8*)&as[R * 32 + ((lg ^ sx) * 8)];
        }
#pragma unroll
        for (int n = 0; n < 4; ++n) {
            const int R = wn * 64 + n * 16 + lm;
            bfr[n] = *(const bf16x8*)&bs[R * 32 + ((lg ^ sx) * 8)];
        }
        // issue deep prefetch (depth 3)
        if (t + 3 < NT) stage(t + 3);

        BARRIER();                               // #1
        WAITLG0();                               // frags in regs
        __builtin_amdgcn_s_setprio(1);
#pragma unroll
        for (int m = 0; m < 4; ++m)
#pragma unroll
            for (int n = 0; n < 4; ++n)
                acc[m][n] = __builtin_amdgcn_mfma_f32_16x16x32_bf16(
                    af[m], bfr[n], acc[m][n], 0, 0, 0);
        __builtin_amdgcn_s_setprio(0);

        // ensure stage(t+1) complete before next phase's ds_read;
        // never drain to 0 mid-loop (counted, tail-stepped 6 -> 3 -> 0)
        if (t + 3 < NT)      { WAITV6(); }
        else if (t + 2 < NT) { WAITV3(); }
        else                 { WAITV0(); }
        BARRIER();                               // #2
    }

    // epilogue: row = by*256+wm*64+m*16+lg*4+j, col = bx*128+wn*64+n*16+lm
#pragma unroll
    for (int n = 0; n < 4; ++n) {
        const long col = bx * 128 + wn * 64 + n * 16 + lm;
        const float bb = bias[col];
#pragma unroll
        for (int m = 0; m < 4; ++m) {
#pragma unroll
            for (int j = 0; j < 4; ++j) {
                const long row = by * 256 + wm * 64 + m * 16 + lg * 4 + j;
                float e = acc[m][n][j] + bb;
                if (EPI == 1) e = fmaxf(e, 0.f);
                if (EPI == 2) {
                    e = 1.f / (1.f + expf(-e));
                    ((float*)Cout)[row * (long)N + col] = e;
                } else {
                    ((u16*)Cout)[row * (long)N + col] = f2bf(e);
                }
            }
        }
    }
}

// ---------------------------------------------------------------------------
// 128^2 bf16 MFMA GEMM for GEMM2 (N=256). T4 counted-vmcnt, swizzled.
// EPI: 0 = bias->bf16
// ---------------------------------------------------------------------------
template <int EPI>
__global__ __launch_bounds__(256)
void gemm_bt_bf16(const u16* __restrict__ A, const u16* __restrict__ Bt,
                  const float* __restrict__ bias, void* __restrict__ Cout,
                  int M, int N, int K)
{
    __shared__ __align__(16) u16 As[3 * 4096];
    __shared__ __align__(16) u16 Bs[3 * 4096];

    const int tid = threadIdx.x;
    const int w = tid >> 6, l = tid & 63;
    const int wr = w >> 1, wc = w & 1;

    const int nbx   = N >> 7;
    const int nwg   = (M >> 7) * nbx;
    const int chunk = nwg >> 3;
    const int wg    = ((int)blockIdx.x & 7) * chunk + ((int)blockIdx.x >> 3);
    const long by   = wg / nbx;
    const long bx   = wg % nbx;

    const int lr  = l >> 2;
    const int lsw = (l & 3) ^ ((l >> 3) & 3);
    const int lg  = l >> 4, lm = l & 15;
    const int sx  = (lm >> 1) & 3;

    const u16* Abase = A  + (size_t)(by * 128) * K;
    const u16* Bbase = Bt + (size_t)(bx * 128) * K;

    f32x4 acc[4][4] = {};

    auto stage = [&](int k0, int b) {
        u16* dA = As + b * 4096;
        u16* dB = Bs + b * 4096;
#pragma unroll
        for (int i = 0; i < 2; ++i) {
            const int seg = w * 2 + i;
            GLD16(Abase + (size_t)(seg * 16 + lr) * K + k0 + lsw * 8, dA + seg * 512);
            GLD16(Bbase + (size_t)(seg * 16 + lr) * K + k0 + lsw * 8, dB + seg * 512);
        }
    };

    const int NT = K >> 5;
    stage(0, 0);
    stage(32, 1);

    int cur = 0, pre = 2;
    for (int t = 0; t < NT; ++t) {
        if (t + 1 < NT) { WAITV4(); } else { WAITV0(); }
        BARRIER();
        if (t + 2 < NT) stage((t + 2) << 5, pre);

        const u16* as = As + cur * 4096;
        const u16* bs = Bs + cur * 4096;
        bf16x8 af[4], bfr[4];
#pragma unroll
        for (int m = 0; m < 4; ++m)
            af[m] = *(const bf16x8*)&as[(wr * 64 + m * 16 + lm) * 32 + ((lg ^ sx) * 8)];
#pragma unroll
        for (int n = 0; n < 4; ++n)
            bfr[n] = *(const bf16x8*)&bs[(wc * 64 + n * 16 + lm) * 32 + ((lg ^ sx) * 8)];
#pragma unroll
        for (int m = 0; m < 4; ++m)
#pragma unroll
            for (int n = 0; n < 4; ++n)
                acc[m][n] = __builtin_amdgcn_mfma_f32_16x16x32_bf16(
                    af[m], bfr[n], acc[m][n], 0, 0, 0);

        cur = (cur == 2) ? 0 : cur + 1;
        pre = (pre == 2) ? 0 : pre + 1;
    }

#pragma unroll
    for (int n = 0; n < 4; ++n) {
        const long col = bx * 128 + wc * 64 + n * 16 + lm;
        const float bb = bias[col];
#pragma unroll
        for (int m = 0; m < 4; ++m) {
#pragma unroll
            for (int j = 0; j < 4; ++j) {
                const long row = by * 128 + wr * 64 + m * 16 + lg * 4 + j;
                float e = acc[m][n][j] + bb;
                if (EPI == 1) e = fmaxf(e, 0.f);
                if (EPI == 2) {
                    e = 1.f / (1.f + expf(-e));
                    ((float*)Cout)[row * (long)N + col] = e;
                } else {
                    ((u16*)Cout)[row * (long)N + col] = f2bf(e);
                }
            }
        }
    }
}

// ---------------------------------------------------------------------------
// VQ phase 1 v2: register-resident A, LDS-streamed codebook (unchanged).
// ---------------------------------------------------------------------------
__global__ __launch_bounds__(256, 2)
void vq_score2(const u16* __restrict__ z, const u16* __restrict__ cbt,
               const float* __restrict__ cn2,
               float* __restrict__ val8, int* __restrict__ idx8)
{
    __shared__ __align__(16) u16 lds[32768];

    const int tid = threadIdx.x;
    const int w = tid >> 6, l = tid & 63;
    const int rq = blockIdx.x >> 3;
    const int q  = blockIdx.x & 7;

    const int st_row8 = tid >> 5;
    const int st_s    = (tid & 31) ^ st_row8;
    const int lg = l >> 4, lm = l & 15;
    const int swz_x = l & 7;

    bf16x8 af[4][8];
    const long zbase_row = (long)rq * 256;
#pragma unroll
    for (int h = 0; h < 2; ++h) {
#pragma unroll
        for (int i = 0; i < 16; ++i) {
            const int row = i * 8 + st_row8;
            const u16* g = z + (zbase_row + h * 128 + row) * DL + st_s * 8;
            GLD16(g, lds + ((size_t)i * 256 + w * 64) * 8);
        }
        __syncthreads();
        if ((w >> 1) == h) {
            const int lrow0 = (w & 1) * 64;
#pragma unroll
            for (int m = 0; m < 4; ++m) {
                const int lrow = lrow0 + m * 16 + lm;
#pragma unroll
                for (int kg = 0; kg < 8; ++kg) {
                    const int s = (kg * 4 + lg) ^ swz_x;
                    af[m][kg] = *(const bf16x8*)&lds[lrow * 256 + s * 8];
                }
            }
        }
        __syncthreads();
    }

    const int code00 = q * (NE / 8);

    float bestv[16];
    int   besti[16];
#pragma unroll
    for (int k = 0; k < 16; ++k) { bestv[k] = 1e30f; besti[k] = 0; }

    auto stage_tile = [&](int t) {
        const int b = t & 1;
#pragma unroll
        for (int i = 0; i < 8; ++i) {
            const int c = i * 8 + st_row8;
            const u16* g = cbt + (size_t)(code00 + t * 64 + c) * DL + st_s * 8;
            GLD16(g, lds + ((size_t)b * 16384 + ((size_t)i * 256 + w * 64) * 8));
        }
    };

    stage_tile(0);
    __syncthreads();

    for (int t = 0; t < 16; ++t) {
        if (t < 15) stage_tile(t + 1);
        const u16* buf = lds + (size_t)(t & 1) * 16384;

#pragma unroll
        for (int n = 0; n < 4; ++n) {
            const int code_g = code00 + t * 64 + n * 16 + lm;
            const float cn2v = cn2[code_g];
            bf16x8 bfr[8];
#pragma unroll
            for (int kg = 0; kg < 8; ++kg) {
                const int lrow = n * 16 + lm;
                const int s = (kg * 4 + lg) ^ swz_x;
                bfr[kg] = *(const bf16x8*)&buf[lrow * 256 + s * 8];
            }
            f32x4 acc[4] = {};
#pragma unroll
            for (int kg = 0; kg < 8; ++kg)
#pragma unroll
                for (int m = 0; m < 4; ++m)
                    acc[m] = __builtin_amdgcn_mfma_f32_16x16x32_bf16(
                        af[m][kg], bfr[kg], acc[m], 0, 0, 0);
#pragma unroll
            for (int m = 0; m < 4; ++m)
#pragma unroll
                for (int j = 0; j < 4; ++j) {
                    const float s = cn2v - acc[m][j];
                    const int k16 = m * 4 + j;
                    if (s < bestv[k16]) { bestv[k16] = s; besti[k16] = code_g; }
                }
        }
        __syncthreads();
    }

#pragma unroll
    for (int off = 1; off < 16; off <<= 1) {
#pragma unroll
        for (int k = 0; k < 16; ++k) {
            const float ov = __shfl_xor(bestv[k], off);
            const int   oi = __shfl_xor(besti[k], off);
            if (ov < bestv[k] || (ov == bestv[k] && oi < besti[k])) {
                bestv[k] = ov; besti[k] = oi;
            }
        }
    }
    if (lm == 0) {
#pragma unroll
        for (int m = 0; m < 4; ++m)
#pragma unroll
            for (int j = 0; j < 4; ++j) {
                const long row = zbase_row + w * 64 + m * 16 + lg * 4 + j;
                val8[(size_t)q * B_ + row] = bestv[m * 4 + j];
                idx8[(size_t)q * B_ + row] = besti[m * 4 + j];
            }
    }
}

// ---------------------------------------------------------------------------
// VQ phase 2: per row pick best of 8 candidates (tie-break lowest idx),
// write final index, accumulate loss partial.
// ---------------------------------------------------------------------------
__global__ __launch_bounds__(256)
void vq_select2(const float* __restrict__ val8, const int* __restrict__ idx8,
                const u16* __restrict__ z, const float* __restrict__ cb,
                int* __restrict__ idxf, float* __restrict__ partial)
{
    __shared__ int   s_idx[256];
    __shared__ float s_red[4];
    const int tid = threadIdx.x;
    const long row = (long)blockIdx.x * 256 + tid;

    float bv = val8[row];
    int   bi = idx8[row];
#pragma unroll
    for (int qq = 1; qq < 8; ++qq) {
        const float v = val8[(size_t)qq * B_ + row];
        const int   i = idx8[(size_t)qq * B_ + row];
        if (v < bv || (v == bv && i < bi)) { bv = v; bi = i; }
    }
    s_idx[tid] = bi;
    idxf[row]  = bi;
    __syncthreads();

    float ls = 0.f;
    const int sub = tid & 7;
#pragma unroll
    for (int pass = 0; pass < 8; ++pass) {
        const int rl = pass * 32 + (tid >> 3);
        const int gi = s_idx[rl];
        const long rg = (long)blockIdx.x * 256 + rl;
#pragma unroll
        for (int tt = 0; tt < 8; ++tt) {
            const int d = sub * 4 + tt * 32;
            float4 c4 = *(const float4*)(cb + (long)gi * DL + d);
            ushort4 zu = *(const ushort4*)(z + rg * DL + d);
            const float dx = c4.x - bf2f(zu.x), dy = c4.y - bf2f(zu.y);
            const float dz = c4.z - bf2f(zu.z), dw = c4.w - bf2f(zu.w);
            ls += dx * dx + dy * dy + dz * dz + dw * dw;
        }
    }
#pragma unroll
    for (int off = 32; off; off >>= 1) ls += __shfl_down(ls, off);
    if ((tid & 63) == 0) s_red[tid >> 6] = ls;
    __syncthreads();
    if (tid == 0)
        partial[blockIdx.x] = s_red[0] + s_red[1] + s_red[2] + s_red[3];
}

// ---------------------------------------------------------------------------
// loss = 1.25 * sum(partial[64]) / (B_*DL)
// ---------------------------------------------------------------------------
__global__ __launch_bounds__(256)
void loss_finalize(const float* __restrict__ partial, float* __restrict__ out)
{
    __shared__ float s_red[4];
    const int tid = threadIdx.x;
    float s = (tid < 64) ? partial[tid] : 0.f;
#pragma unroll
    for (int off = 32; off; off >>= 1) s += __shfl_down(s, off);
    if ((tid & 63) == 0) s_red[tid >> 6] = s;
    __syncthreads();
    if (tid == 0)
        out[0] = 1.25f * (s_red[0] + s_red[1] + s_red[2] + s_red[3])
                 / (float)((long)B_ * DL);
}

// ---------------------------------------------------------------------------
// gather: out[row] = Xcode[idxf[row]]  (1024 f32/row; one wave per row).
// ---------------------------------------------------------------------------
__global__ __launch_bounds__(256)
void gather_rows(const float* __restrict__ Xcode, const int* __restrict__ idxf,
                 float* __restrict__ out)
{
    const int tid  = threadIdx.x;
    const int lane = tid & 63;
    const long row = (long)blockIdx.x * 4 + (tid >> 6);
    const long gi  = idxf[row];
    const float* src = Xcode + gi * DIN;
    float*       dst = out + row * DIN;
#pragma unroll
    for (int t = 0; t < 4; ++t) {
        const int d = lane * 4 + t * 256;
        *(float4*)(dst + d) = *(const float4*)(src + d);
    }
}

// ---------------------------------------------------------------------------
extern "C" void kernel_launch(void* const* d_in, const int* in_sizes, int n_in,
                              void* d_out, int out_size, void* d_ws, size_t ws_size,
                              hipStream_t stream)
{
    const float* x   = (const float*)d_in[0];
    const float* ew1 = (const float*)d_in[1];
    const float* eb1 = (const float*)d_in[2];
    const float* ew2 = (const float*)d_in[3];
    const float* eb2 = (const float*)d_in[4];
    const float* cbk = (const float*)d_in[5];
    const float* dw1 = (const float*)d_in[6];
    const float* db1 = (const float*)d_in[7];
    const float* dw2 = (const float*)d_in[8];
    const float* db2 = (const float*)d_in[9];
    float* out = (float*)d_out;

    char* p = (char*)d_ws;
    auto alloc = [&](size_t bytes) {
        char* r = p; p += (bytes + 255) & ~(size_t)255; return r;
    };
    u16*   x_bf  = (u16*)alloc((size_t)B_ * DIN * 2);
    u16*   h_bf  = (u16*)alloc((size_t)B_ * DH * 2);   // encoder h; then Hcode
    u16*   z_bf  = (u16*)alloc((size_t)B_ * DL * 2);
    u16*   cb_bf = (u16*)alloc((size_t)NE * DL * 2);
    u16*   w1t   = (u16*)alloc((size_t)DH * DIN * 2);  // [N][K] bf16
    u16*   w2t   = (u16*)alloc((size_t)DL * DH * 2);
    u16*   wd1t  = (u16*)alloc((size_t)DH * DL * 2);
    u16*   wd2t  = (u16*)alloc((size_t)DIN * DH * 2);
    float* Xcode = (float*)alloc((size_t)NE * DIN * 4);   // per-code recon
    float* cn2   = (float*)alloc((size_t)NE * 4);
    float* val8  = (float*)alloc((size_t)8 * B_ * 4);
    int*   idx8  = (int*)alloc((size_t)8 * B_ * 4);
    int*   idxf  = (int*)alloc((size_t)B_ * 4);
    float* part  = (float*)alloc(64 * 4);

    // casts / transposes (weights -> [N][K] bf16)
    cast_bf16<<<(size_t)B_ * DIN / 1024, 256, 0, stream>>>(x, x_bf);
    cast_bf16<<<(size_t)NE * DL / 1024, 256, 0, stream>>>(cbk, cb_bf);
    transpose_cast<<<dim3(DH / 32, DIN / 32), 256, 0, stream>>>(ew1, w1t, DIN, DH);
    transpose_cast<<<dim3(DL / 32, DH / 32), 256, 0, stream>>>(ew2, w2t, DH, DL);
    transpose_cast<<<dim3(DH / 32, DL / 32), 256, 0, stream>>>(dw1, wd1t, DL, DH);
    transpose_cast<<<dim3(DIN / 32, DH / 32), 256, 0, stream>>>(dw2, wd2t, DH, DIN);
    cn2_kernel<<<NE / 4, 256, 0, stream>>>(cbk, cn2);

    // encoder (gemm1 on the 8-phase kernel)
    gemm_8ph_bf16<1><<<(B_ / 256) * (DH / 128), 512, 0, stream>>>(
        x_bf, w1t, eb1, h_bf, B_, DH, DIN);
    gemm_bt_bf16<0><<<(B_ / 128) * (DL / 128), 256, 0, stream>>>(
        h_bf, w2t, eb2, z_bf, B_, DL, DH);

    // vector quantizer -> final index per row + loss
    vq_score2<<<512, 256, 0, stream>>>(z_bf, cb_bf, cn2, val8, idx8);
    vq_select2<<<B_ / 256, 256, 0, stream>>>(val8, idx8, z_bf, cbk, idxf, part);
    loss_finalize<<<1, 256, 0, stream>>>(part, out + (size_t)B_ * DIN);

    // decoder per CODE (8192 rows) on the 8-phase kernel, then gather.
    gemm_8ph_bf16<1><<<(NE / 256) * (DH / 128), 512, 0, stream>>>(
        cb_bf, wd1t, db1, h_bf, NE, DH, DL);
    gemm_8ph_bf16<2><<<(NE / 256) * (DIN / 128), 512, 0, stream>>>(
        h_bf, wd2t, db2, Xcode, NE, DIN, DH);
    gather_rows<<<B_ / 4, 256, 0, stream>>>(Xcode, idxf, out);
}

// Round 12
// 313.206 us; speedup vs baseline: 1.0978x; 1.0536x over previous
//
#include <hip/hip_runtime.h>
#include <math.h>

typedef unsigned short u16;
typedef __bf16 bf16x8 __attribute__((ext_vector_type(8)));
typedef float  f32x4  __attribute__((ext_vector_type(4)));

constexpr int B_  = 16384;   // batch
constexpr int DIN = 1024;    // input dim
constexpr int DH  = 2048;    // hidden dim
constexpr int DL  = 256;     // latent dim
constexpr int NE  = 8192;    // codebook entries

__device__ __forceinline__ u16 f2bf(float f) {     // RTNE float->bf16
    union { float f; unsigned u; } v; v.f = f;
    unsigned r = v.u + 0x7fffu + ((v.u >> 16) & 1u);
    return (u16)(r >> 16);
}
__device__ __forceinline__ float bf2f(u16 h) {
    union { unsigned u; float f; } v; v.u = ((unsigned)h) << 16;
    return v.f;
}

#define GLD16(gp, lp)                                                  \
    __builtin_amdgcn_global_load_lds(                                  \
        (__attribute__((address_space(1))) void*)(gp),                 \
        (__attribute__((address_space(3))) void*)(lp), 16, 0, 0)

#define SCHED0() __builtin_amdgcn_sched_barrier(0)
#define BARRIER() do { SCHED0(); __builtin_amdgcn_s_barrier(); SCHED0(); } while (0)
#define WAITV0() asm volatile("s_waitcnt vmcnt(0)" ::: "memory")
#define WAITV3() asm volatile("s_waitcnt vmcnt(3)" ::: "memory")
#define WAITV4() asm volatile("s_waitcnt vmcnt(4)" ::: "memory")

// ---------------------------------------------------------------------------
// Fused prologue: one launch replacing 7 (2 casts, 4 transpose-casts, cn2).
// Dispatch by blockIdx range; per-element math verbatim from the original
// kernels -> bitwise-identical outputs.
// Block ranges (256 threads each):
//   [0, 16384)            cast x   -> x_bf      (4 f32/thread)
//   [16384, 18432)        cast cb  -> cb_bf
//   [18432, 20480)        transpose ew1 [1024x2048] -> w1t   (gx=64, gy=32)
//   [20480, 20992)        transpose ew2 [2048x256]  -> w2t   (gx=8,  gy=64)
//   [20992, 21504)        transpose dw1 [256x2048]  -> wd1t  (gx=64, gy=8)
//   [21504, 23552)        transpose dw2 [2048x1024] -> wd2t  (gx=32, gy=64)
//   [23552, 25600)        cn2 (one wave per code, 4 codes/block)
// ---------------------------------------------------------------------------
__device__ __forceinline__ void dev_cast(const float* __restrict__ in,
                                         u16* __restrict__ out, long blk)
{
    const size_t i = ((size_t)blk * 256 + threadIdx.x) * 4;
    float4 v = *(const float4*)(in + i);
    ushort4 o;
    o.x = f2bf(v.x); o.y = f2bf(v.y); o.z = f2bf(v.z); o.w = f2bf(v.w);
    *(ushort4*)(out + i) = o;
}

__device__ __forceinline__ void dev_transpose(const float* __restrict__ in,
                                              u16* __restrict__ out,
                                              int R, int C, long bx, long by,
                                              float (*t)[33])
{
    const int tx = threadIdx.x & 31, ty = threadIdx.x >> 5;
#pragma unroll
    for (int p = 0; p < 4; ++p)
        t[ty + p * 8][tx] = in[(by * 32 + ty + p * 8) * (long)C + bx * 32 + tx];
    __syncthreads();
#pragma unroll
    for (int p = 0; p < 4; ++p)
        out[(bx * 32 + ty + p * 8) * (long)R + by * 32 + tx] = f2bf(t[tx][ty + p * 8]);
}

__global__ __launch_bounds__(256)
void prep_fused(const float* __restrict__ x,   u16* __restrict__ x_bf,
                const float* __restrict__ cb,  u16* __restrict__ cb_bf,
                const float* __restrict__ ew1, u16* __restrict__ w1t,
                const float* __restrict__ ew2, u16* __restrict__ w2t,
                const float* __restrict__ dw1, u16* __restrict__ wd1t,
                const float* __restrict__ dw2, u16* __restrict__ wd2t,
                float* __restrict__ cn2)
{
    __shared__ float t[32][33];
    const long b = blockIdx.x;

    if (b < 16384) {                       // cast x
        dev_cast(x, x_bf, b);
    } else if (b < 18432) {                // cast cb
        dev_cast(cb, cb_bf, b - 16384);
    } else if (b < 20480) {                // ew1 [1024,2048] -> w1t, gx=64
        const long r = b - 18432;
        dev_transpose(ew1, w1t, DIN, DH, r % 64, r / 64, t);
    } else if (b < 20992) {                // ew2 [2048,256] -> w2t, gx=8
        const long r = b - 20480;
        dev_transpose(ew2, w2t, DH, DL, r % 8, r / 8, t);
    } else if (b < 21504) {                // dw1 [256,2048] -> wd1t, gx=64
        const long r = b - 20992;
        dev_transpose(dw1, wd1t, DL, DH, r % 64, r / 64, t);
    } else if (b < 23552) {                // dw2 [2048,1024] -> wd2t, gx=32
        const long r = b - 21504;
        dev_transpose(dw2, wd2t, DH, DIN, r % 32, r / 32, t);
    } else {                               // cn2: 4 codes/block
        const long r = b - 23552;
        const int code = (int)((r * 256 + threadIdx.x) >> 6);
        const int lane = threadIdx.x & 63;
        float4 v = *(const float4*)(cb + (long)code * DL + lane * 4);
        float s = fmaf(v.x, v.x, fmaf(v.y, v.y, fmaf(v.z, v.z, v.w * v.w)));
#pragma unroll
        for (int off = 32; off; off >>= 1) s += __shfl_down(s, off);
        if (lane == 0) cn2[code] = 0.5f * s;
    }
}

// ---------------------------------------------------------------------------
// BIG bf16 MFMA GEMM (r9-proven best): BM=256, BN=128, BK=32, 512 threads =
// 8 waves (4M x 2N). T4 counted-vmcnt pipeline, 3 LDS buffers (72KB,
// 2 blocks/CU), depth-2 prefetch, one raw s_barrier per K-step.
// Both-sides XOR swizzle (conflict-free). T1 XCD remap (nwg % 8 == 0).
// K-accumulation order fixed -> per-row results bitwise-stable.
// EPI: 1 = bias+relu->bf16, 2 = bias+sigmoid->f32
// ---------------------------------------------------------------------------
template <int EPI>
__global__ __launch_bounds__(512, 4)
void gemm_big_bf16(const u16* __restrict__ A, const u16* __restrict__ Bt,
                   const float* __restrict__ bias, void* __restrict__ Cout,
                   int M, int N, int K)
{
    __shared__ __align__(16) u16 As[3 * 8192];   // 3 x 16 KB (256 rows x 32)
    __shared__ __align__(16) u16 Bs[3 * 4096];   // 3 x  8 KB (128 rows x 32)

    const int tid = threadIdx.x;
    const int w = tid >> 6, l = tid & 63;
    const int wm = w >> 1, wn = w & 1;

    const int nbx   = N >> 7;
    const int nwg   = (M >> 8) * nbx;
    const int chunk = nwg >> 3;
    const int wg    = ((int)blockIdx.x & 7) * chunk + ((int)blockIdx.x >> 3);
    const long by   = wg / nbx;
    const long bx   = wg % nbx;

    const int lr  = l >> 2;                      // row within 16-row segment
    const int lsw = (l & 3) ^ ((l >> 3) & 3);    // swizzled source chunk
    const int lg  = l >> 4, lm = l & 15;         // frag k-group / row index
    const int sx  = (lm >> 1) & 3;               // read-side xor key

    const u16* Abase = A  + (size_t)(by * 256) * K;
    const u16* Bbase = Bt + (size_t)(bx * 128) * K;

    f32x4 acc[4][4] = {};

    auto stage = [&](int k0, int b) {
        u16* dA = As + b * 8192;
        u16* dB = Bs + b * 4096;
#pragma unroll
        for (int i = 0; i < 2; ++i) {
            const int seg = w * 2 + i;           // 0..15 -> 16 rows each
            GLD16(Abase + (size_t)(seg * 16 + lr) * K + k0 + lsw * 8,
                  dA + seg * 512);
        }
        GLD16(Bbase + (size_t)(w * 16 + lr) * K + k0 + lsw * 8,
              dB + w * 512);
    };

    const int NT = K >> 5;
    stage(0, 0);
    stage(32, 1);

    int cur = 0, pre = 2;
    for (int t = 0; t < NT; ++t) {
        if (t + 1 < NT) { WAITV3(); } else { WAITV0(); }
        BARRIER();
        if (t + 2 < NT) stage((t + 2) << 5, pre);

        const u16* as = As + cur * 8192;
        const u16* bs = Bs + cur * 4096;
        bf16x8 af[4], bfr[4];
#pragma unroll
        for (int m = 0; m < 4; ++m) {
            const int R = wm * 64 + m * 16 + lm;
            af[m] = *(const bf16x8*)&as[R * 32 + ((lg ^ sx) * 8)];
        }
#pragma unroll
        for (int n = 0; n < 4; ++n) {
            const int R = wn * 64 + n * 16 + lm;
            bfr[n] = *(const bf16x8*)&bs[R * 32 + ((lg ^ sx) * 8)];
        }
#pragma unroll
        for (int m = 0; m < 4; ++m)
#pragma unroll
            for (int n = 0; n < 4; ++n)
                acc[m][n] = __builtin_amdgcn_mfma_f32_16x16x32_bf16(
                    af[m], bfr[n], acc[m][n], 0, 0, 0);

        cur = (cur == 2) ? 0 : cur + 1;
        pre = (pre == 2) ? 0 : pre + 1;
    }

#pragma unroll
    for (int n = 0; n < 4; ++n) {
        const long col = bx * 128 + wn * 64 + n * 16 + lm;
        const float bb = bias[col];
#pragma unroll
        for (int m = 0; m < 4; ++m) {
#pragma unroll
            for (int j = 0; j < 4; ++j) {
                const long row = by * 256 + wm * 64 + m * 16 + lg * 4 + j;
                float e = acc[m][n][j] + bb;
                if (EPI == 1) e = fmaxf(e, 0.f);
                if (EPI == 2) {
                    e = 1.f / (1.f + expf(-e));
                    ((float*)Cout)[row * (long)N + col] = e;
                } else {
                    ((u16*)Cout)[row * (long)N + col] = f2bf(e);
                }
            }
        }
    }
}

// ---------------------------------------------------------------------------
// 128^2 bf16 MFMA GEMM for GEMM2 (N=256). T4 counted-vmcnt, swizzled.
// EPI: 0 = bias->bf16
// ---------------------------------------------------------------------------
template <int EPI>
__global__ __launch_bounds__(256)
void gemm_bt_bf16(const u16* __restrict__ A, const u16* __restrict__ Bt,
                  const float* __restrict__ bias, void* __restrict__ Cout,
                  int M, int N, int K)
{
    __shared__ __align__(16) u16 As[3 * 4096];
    __shared__ __align__(16) u16 Bs[3 * 4096];

    const int tid = threadIdx.x;
    const int w = tid >> 6, l = tid & 63;
    const int wr = w >> 1, wc = w & 1;

    const int nbx   = N >> 7;
    const int nwg   = (M >> 7) * nbx;
    const int chunk = nwg >> 3;
    const int wg    = ((int)blockIdx.x & 7) * chunk + ((int)blockIdx.x >> 3);
    const long by   = wg / nbx;
    const long bx   = wg % nbx;

    const int lr  = l >> 2;
    const int lsw = (l & 3) ^ ((l >> 3) & 3);
    const int lg  = l >> 4, lm = l & 15;
    const int sx  = (lm >> 1) & 3;

    const u16* Abase = A  + (size_t)(by * 128) * K;
    const u16* Bbase = Bt + (size_t)(bx * 128) * K;

    f32x4 acc[4][4] = {};

    auto stage = [&](int k0, int b) {
        u16* dA = As + b * 4096;
        u16* dB = Bs + b * 4096;
#pragma unroll
        for (int i = 0; i < 2; ++i) {
            const int seg = w * 2 + i;
            GLD16(Abase + (size_t)(seg * 16 + lr) * K + k0 + lsw * 8, dA + seg * 512);
            GLD16(Bbase + (size_t)(seg * 16 + lr) * K + k0 + lsw * 8, dB + seg * 512);
        }
    };

    const int NT = K >> 5;
    stage(0, 0);
    stage(32, 1);

    int cur = 0, pre = 2;
    for (int t = 0; t < NT; ++t) {
        if (t + 1 < NT) { WAITV4(); } else { WAITV0(); }
        BARRIER();
        if (t + 2 < NT) stage((t + 2) << 5, pre);

        const u16* as = As + cur * 4096;
        const u16* bs = Bs + cur * 4096;
        bf16x8 af[4], bfr[4];
#pragma unroll
        for (int m = 0; m < 4; ++m)
            af[m] = *(const bf16x8*)&as[(wr * 64 + m * 16 + lm) * 32 + ((lg ^ sx) * 8)];
#pragma unroll
        for (int n = 0; n < 4; ++n)
            bfr[n] = *(const bf16x8*)&bs[(wc * 64 + n * 16 + lm) * 32 + ((lg ^ sx) * 8)];
#pragma unroll
        for (int m = 0; m < 4; ++m)
#pragma unroll
            for (int n = 0; n < 4; ++n)
                acc[m][n] = __builtin_amdgcn_mfma_f32_16x16x32_bf16(
                    af[m], bfr[n], acc[m][n], 0, 0, 0);

        cur = (cur == 2) ? 0 : cur + 1;
        pre = (pre == 2) ? 0 : pre + 1;
    }

#pragma unroll
    for (int n = 0; n < 4; ++n) {
        const long col = bx * 128 + wc * 64 + n * 16 + lm;
        const float bb = bias[col];
#pragma unroll
        for (int m = 0; m < 4; ++m) {
#pragma unroll
            for (int j = 0; j < 4; ++j) {
                const long row = by * 128 + wr * 64 + m * 16 + lg * 4 + j;
                float e = acc[m][n][j] + bb;
                if (EPI == 1) e = fmaxf(e, 0.f);
                if (EPI == 2) {
                    e = 1.f / (1.f + expf(-e));
                    ((float*)Cout)[row * (long)N + col] = e;
                } else {
                    ((u16*)Cout)[row * (long)N + col] = f2bf(e);
                }
            }
        }
    }
}

// ---------------------------------------------------------------------------
// VQ phase 1 v2: register-resident A, LDS-streamed codebook (unchanged).
// ---------------------------------------------------------------------------
__global__ __launch_bounds__(256, 2)
void vq_score2(const u16* __restrict__ z, const u16* __restrict__ cbt,
               const float* __restrict__ cn2,
               float* __restrict__ val8, int* __restrict__ idx8)
{
    __shared__ __align__(16) u16 lds[32768];

    const int tid = threadIdx.x;
    const int w = tid >> 6, l = tid & 63;
    const int rq = blockIdx.x >> 3;
    const int q  = blockIdx.x & 7;

    const int st_row8 = tid >> 5;
    const int st_s    = (tid & 31) ^ st_row8;
    const int lg = l >> 4, lm = l & 15;
    const int swz_x = l & 7;

    bf16x8 af[4][8];
    const long zbase_row = (long)rq * 256;
#pragma unroll
    for (int h = 0; h < 2; ++h) {
#pragma unroll
        for (int i = 0; i < 16; ++i) {
            const int row = i * 8 + st_row8;
            const u16* g = z + (zbase_row + h * 128 + row) * DL + st_s * 8;
            GLD16(g, lds + ((size_t)i * 256 + w * 64) * 8);
        }
        __syncthreads();
        if ((w >> 1) == h) {
            const int lrow0 = (w & 1) * 64;
#pragma unroll
            for (int m = 0; m < 4; ++m) {
                const int lrow = lrow0 + m * 16 + lm;
#pragma unroll
                for (int kg = 0; kg < 8; ++kg) {
                    const int s = (kg * 4 + lg) ^ swz_x;
                    af[m][kg] = *(const bf16x8*)&lds[lrow * 256 + s * 8];
                }
            }
        }
        __syncthreads();
    }

    const int code00 = q * (NE / 8);

    float bestv[16];
    int   besti[16];
#pragma unroll
    for (int k = 0; k < 16; ++k) { bestv[k] = 1e30f; besti[k] = 0; }

    auto stage_tile = [&](int t) {
        const int b = t & 1;
#pragma unroll
        for (int i = 0; i < 8; ++i) {
            const int c = i * 8 + st_row8;
            const u16* g = cbt + (size_t)(code00 + t * 64 + c) * DL + st_s * 8;
            GLD16(g, lds + ((size_t)b * 16384 + ((size_t)i * 256 + w * 64) * 8));
        }
    };

    stage_tile(0);
    __syncthreads();

    for (int t = 0; t < 16; ++t) {
        if (t < 15) stage_tile(t + 1);
        const u16* buf = lds + (size_t)(t & 1) * 16384;

#pragma unroll
        for (int n = 0; n < 4; ++n) {
            const int code_g = code00 + t * 64 + n * 16 + lm;
            const float cn2v = cn2[code_g];
            bf16x8 bfr[8];
#pragma unroll
            for (int kg = 0; kg < 8; ++kg) {
                const int lrow = n * 16 + lm;
                const int s = (kg * 4 + lg) ^ swz_x;
                bfr[kg] = *(const bf16x8*)&buf[lrow * 256 + s * 8];
            }
            f32x4 acc[4] = {};
#pragma unroll
            for (int kg = 0; kg < 8; ++kg)
#pragma unroll
                for (int m = 0; m < 4; ++m)
                    acc[m] = __builtin_amdgcn_mfma_f32_16x16x32_bf16(
                        af[m][kg], bfr[kg], acc[m], 0, 0, 0);
#pragma unroll
            for (int m = 0; m < 4; ++m)
#pragma unroll
                for (int j = 0; j < 4; ++j) {
                    const float s = cn2v - acc[m][j];
                    const int k16 = m * 4 + j;
                    if (s < bestv[k16]) { bestv[k16] = s; besti[k16] = code_g; }
                }
        }
        __syncthreads();
    }

#pragma unroll
    for (int off = 1; off < 16; off <<= 1) {
#pragma unroll
        for (int k = 0; k < 16; ++k) {
            const float ov = __shfl_xor(bestv[k], off);
            const int   oi = __shfl_xor(besti[k], off);
            if (ov < bestv[k] || (ov == bestv[k] && oi < besti[k])) {
                bestv[k] = ov; besti[k] = oi;
            }
        }
    }
    if (lm == 0) {
#pragma unroll
        for (int m = 0; m < 4; ++m)
#pragma unroll
            for (int j = 0; j < 4; ++j) {
                const long row = zbase_row + w * 64 + m * 16 + lg * 4 + j;
                val8[(size_t)q * B_ + row] = bestv[m * 4 + j];
                idx8[(size_t)q * B_ + row] = besti[m * 4 + j];
            }
    }
}

// ---------------------------------------------------------------------------
// VQ phase 2: per row pick best of 8 candidates (tie-break lowest idx),
// write final index, accumulate loss partial.
// ---------------------------------------------------------------------------
__global__ __launch_bounds__(256)
void vq_select2(const float* __restrict__ val8, const int* __restrict__ idx8,
                const u16* __restrict__ z, const float* __restrict__ cb,
                int* __restrict__ idxf, float* __restrict__ partial)
{
    __shared__ int   s_idx[256];
    __shared__ float s_red[4];
    const int tid = threadIdx.x;
    const long row = (long)blockIdx.x * 256 + tid;

    float bv = val8[row];
    int   bi = idx8[row];
#pragma unroll
    for (int qq = 1; qq < 8; ++qq) {
        const float v = val8[(size_t)qq * B_ + row];
        const int   i = idx8[(size_t)qq * B_ + row];
        if (v < bv || (v == bv && i < bi)) { bv = v; bi = i; }
    }
    s_idx[tid] = bi;
    idxf[row]  = bi;
    __syncthreads();

    float ls = 0.f;
    const int sub = tid & 7;
#pragma unroll
    for (int pass = 0; pass < 8; ++pass) {
        const int rl = pass * 32 + (tid >> 3);
        const int gi = s_idx[rl];
        const long rg = (long)blockIdx.x * 256 + rl;
#pragma unroll
        for (int tt = 0; tt < 8; ++tt) {
            const int d = sub * 4 + tt * 32;
            float4 c4 = *(const float4*)(cb + (long)gi * DL + d);
            ushort4 zu = *(const ushort4*)(z + rg * DL + d);
            const float dx = c4.x - bf2f(zu.x), dy = c4.y - bf2f(zu.y);
            const float dz = c4.z - bf2f(zu.z), dw = c4.w - bf2f(zu.w);
            ls += dx * dx + dy * dy + dz * dz + dw * dw;
        }
    }
#pragma unroll
    for (int off = 32; off; off >>= 1) ls += __shfl_down(ls, off);
    if ((tid & 63) == 0) s_red[tid >> 6] = ls;
    __syncthreads();
    if (tid == 0)
        partial[blockIdx.x] = s_red[0] + s_red[1] + s_red[2] + s_red[3];
}

// ---------------------------------------------------------------------------
// loss = 1.25 * sum(partial[64]) / (B_*DL)
// ---------------------------------------------------------------------------
__global__ __launch_bounds__(256)
void loss_finalize(const float* __restrict__ partial, float* __restrict__ out)
{
    __shared__ float s_red[4];
    const int tid = threadIdx.x;
    float s = (tid < 64) ? partial[tid] : 0.f;
#pragma unroll
    for (int off = 32; off; off >>= 1) s += __shfl_down(s, off);
    if ((tid & 63) == 0) s_red[tid >> 6] = s;
    __syncthreads();
    if (tid == 0)
        out[0] = 1.25f * (s_red[0] + s_red[1] + s_red[2] + s_red[3])
                 / (float)((long)B_ * DL);
}

// ---------------------------------------------------------------------------
// gather: out[row] = Xcode[idxf[row]]  (1024 f32/row; one wave per row).
// ---------------------------------------------------------------------------
__global__ __launch_bounds__(256)
void gather_rows(const float* __restrict__ Xcode, const int* __restrict__ idxf,
                 float* __restrict__ out)
{
    const int tid  = threadIdx.x;
    const int lane = tid & 63;
    const long row = (long)blockIdx.x * 4 + (tid >> 6);
    const long gi  = idxf[row];
    const float* src = Xcode + gi * DIN;
    float*       dst = out + row * DIN;
#pragma unroll
    for (int t = 0; t < 4; ++t) {
        const int d = lane * 4 + t * 256;
        *(float4*)(dst + d) = *(const float4*)(src + d);
    }
}

// ---------------------------------------------------------------------------
extern "C" void kernel_launch(void* const* d_in, const int* in_sizes, int n_in,
                              void* d_out, int out_size, void* d_ws, size_t ws_size,
                              hipStream_t stream)
{
    const float* x   = (const float*)d_in[0];
    const float* ew1 = (const float*)d_in[1];
    const float* eb1 = (const float*)d_in[2];
    const float* ew2 = (const float*)d_in[3];
    const float* eb2 = (const float*)d_in[4];
    const float* cbk = (const float*)d_in[5];
    const float* dw1 = (const float*)d_in[6];
    const float* db1 = (const float*)d_in[7];
    const float* dw2 = (const float*)d_in[8];
    const float* db2 = (const float*)d_in[9];
    float* out = (float*)d_out;

    char* p = (char*)d_ws;
    auto alloc = [&](size_t bytes) {
        char* r = p; p += (bytes + 255) & ~(size_t)255; return r;
    };
    u16*   x_bf  = (u16*)alloc((size_t)B_ * DIN * 2);
    u16*   h_bf  = (u16*)alloc((size_t)B_ * DH * 2);   // encoder h; then Hcode
    u16*   z_bf  = (u16*)alloc((size_t)B_ * DL * 2);
    u16*   cb_bf = (u16*)alloc((size_t)NE * DL * 2);
    u16*   w1t   = (u16*)alloc((size_t)DH * DIN * 2);  // [N][K] bf16
    u16*   w2t   = (u16*)alloc((size_t)DL * DH * 2);
    u16*   wd1t  = (u16*)alloc((size_t)DH * DL * 2);
    u16*   wd2t  = (u16*)alloc((size_t)DIN * DH * 2);
    float* Xcode = (float*)alloc((size_t)NE * DIN * 4);   // per-code recon
    float* cn2   = (float*)alloc((size_t)NE * 4);
    float* val8  = (float*)alloc((size_t)8 * B_ * 4);
    int*   idx8  = (int*)alloc((size_t)8 * B_ * 4);
    int*   idxf  = (int*)alloc((size_t)B_ * 4);
    float* part  = (float*)alloc(64 * 4);

    // fused prologue: casts, weight transposes, cn2 (one launch)
    prep_fused<<<25600, 256, 0, stream>>>(x, x_bf, cbk, cb_bf,
                                          ew1, w1t, ew2, w2t,
                                          dw1, wd1t, dw2, wd2t, cn2);

    // encoder
    gemm_big_bf16<1><<<(B_ / 256) * (DH / 128), 512, 0, stream>>>(
        x_bf, w1t, eb1, h_bf, B_, DH, DIN);
    gemm_bt_bf16<0><<<(B_ / 128) * (DL / 128), 256, 0, stream>>>(
        h_bf, w2t, eb2, z_bf, B_, DL, DH);

    // vector quantizer -> final index per row + loss
    vq_score2<<<512, 256, 0, stream>>>(z_bf, cb_bf, cn2, val8, idx8);
    vq_select2<<<B_ / 256, 256, 0, stream>>>(val8, idx8, z_bf, cbk, idxf, part);
    loss_finalize<<<1, 256, 0, stream>>>(part, out + (size_t)B_ * DIN);

    // decoder per CODE (8192 rows), then gather rows by index.
    gemm_big_bf16<1><<<(NE / 256) * (DH / 128), 512, 0, stream>>>(
        cb_bf, wd1t, db1, h_bf, NE, DH, DL);
    gemm_big_bf16<2><<<(NE / 256) * (DIN / 128), 512, 0, stream>>>(
        h_bf, wd2t, db2, Xcode, NE, DIN, DH);
    gather_rows<<<B_ / 4, 256, 0, stream>>>(Xcode, idxf, out);
}

// Round 13
// 300.260 us; speedup vs baseline: 1.1451x; 1.0431x over previous
//
#include <hip/hip_runtime.h>
#include <math.h>

typedef unsigned short u16;
typedef __bf16 bf16x8 __attribute__((ext_vector_type(8)));
typedef float  f32x4  __attribute__((ext_vector_type(4)));

constexpr int B_  = 16384;   // batch
constexpr int DIN = 1024;    // input dim
constexpr int DH  = 2048;    // hidden dim
constexpr int DL  = 256;     // latent dim
constexpr int NE  = 8192;    // codebook entries

__device__ __forceinline__ u16 f2bf(float f) {     // RTNE float->bf16
    union { float f; unsigned u; } v; v.f = f;
    unsigned r = v.u + 0x7fffu + ((v.u >> 16) & 1u);
    return (u16)(r >> 16);
}
__device__ __forceinline__ float bf2f(u16 h) {
    union { unsigned u; float f; } v; v.u = ((unsigned)h) << 16;
    return v.f;
}

#define GLD16(gp, lp)                                                  \
    __builtin_amdgcn_global_load_lds(                                  \
        (__attribute__((address_space(1))) void*)(gp),                 \
        (__attribute__((address_space(3))) void*)(lp), 16, 0, 0)

#define SCHED0() __builtin_amdgcn_sched_barrier(0)
#define BARRIER() do { SCHED0(); __builtin_amdgcn_s_barrier(); SCHED0(); } while (0)
#define WAITV0() asm volatile("s_waitcnt vmcnt(0)" ::: "memory")
#define WAITV3() asm volatile("s_waitcnt vmcnt(3)" ::: "memory")

// ---------------------------------------------------------------------------
// Fused prologue: one launch (2 casts, 4 transpose-casts, cn2) — r12-proven.
// ---------------------------------------------------------------------------
__device__ __forceinline__ void dev_cast(const float* __restrict__ in,
                                         u16* __restrict__ out, long blk)
{
    const size_t i = ((size_t)blk * 256 + threadIdx.x) * 4;
    float4 v = *(const float4*)(in + i);
    ushort4 o;
    o.x = f2bf(v.x); o.y = f2bf(v.y); o.z = f2bf(v.z); o.w = f2bf(v.w);
    *(ushort4*)(out + i) = o;
}

__device__ __forceinline__ void dev_transpose(const float* __restrict__ in,
                                              u16* __restrict__ out,
                                              int R, int C, long bx, long by,
                                              float (*t)[33])
{
    const int tx = threadIdx.x & 31, ty = threadIdx.x >> 5;
#pragma unroll
    for (int p = 0; p < 4; ++p)
        t[ty + p * 8][tx] = in[(by * 32 + ty + p * 8) * (long)C + bx * 32 + tx];
    __syncthreads();
#pragma unroll
    for (int p = 0; p < 4; ++p)
        out[(bx * 32 + ty + p * 8) * (long)R + by * 32 + tx] = f2bf(t[tx][ty + p * 8]);
}

__global__ __launch_bounds__(256)
void prep_fused(const float* __restrict__ x,   u16* __restrict__ x_bf,
                const float* __restrict__ cb,  u16* __restrict__ cb_bf,
                const float* __restrict__ ew1, u16* __restrict__ w1t,
                const float* __restrict__ ew2, u16* __restrict__ w2t,
                const float* __restrict__ dw1, u16* __restrict__ wd1t,
                const float* __restrict__ dw2, u16* __restrict__ wd2t,
                float* __restrict__ cn2)
{
    __shared__ float t[32][33];
    const long b = blockIdx.x;

    if (b < 16384) {                       // cast x
        dev_cast(x, x_bf, b);
    } else if (b < 18432) {                // cast cb
        dev_cast(cb, cb_bf, b - 16384);
    } else if (b < 20480) {                // ew1 [1024,2048] -> w1t, gx=64
        const long r = b - 18432;
        dev_transpose(ew1, w1t, DIN, DH, r % 64, r / 64, t);
    } else if (b < 20992) {                // ew2 [2048,256] -> w2t, gx=8
        const long r = b - 20480;
        dev_transpose(ew2, w2t, DH, DL, r % 8, r / 8, t);
    } else if (b < 21504) {                // dw1 [256,2048] -> wd1t, gx=64
        const long r = b - 20992;
        dev_transpose(dw1, wd1t, DL, DH, r % 64, r / 64, t);
    } else if (b < 23552) {                // dw2 [2048,1024] -> wd2t, gx=32
        const long r = b - 21504;
        dev_transpose(dw2, wd2t, DH, DIN, r % 32, r / 32, t);
    } else {                               // cn2: 4 codes/block
        const long r = b - 23552;
        const int code = (int)((r * 256 + threadIdx.x) >> 6);
        const int lane = threadIdx.x & 63;
        float4 v = *(const float4*)(cb + (long)code * DL + lane * 4);
        float s = fmaf(v.x, v.x, fmaf(v.y, v.y, fmaf(v.z, v.z, v.w * v.w)));
#pragma unroll
        for (int off = 32; off; off >>= 1) s += __shfl_down(s, off);
        if (lane == 0) cn2[code] = 0.5f * s;
    }
}

// ---------------------------------------------------------------------------
// BIG bf16 MFMA GEMM (r9-proven): BM=256, BN=128, BK=32, 512 threads =
// 8 waves (4M x 2N). T4 counted-vmcnt, 3 LDS buffers (72KB, 2 blocks/CU),
// depth-2 prefetch, one raw s_barrier per K-step, both-sides XOR swizzle,
// T1 XCD remap. Used for gemm1 (grid 2048) and dec1 (grid 512).
// EPI: 1 = bias+relu->bf16, 2 = bias+sigmoid->f32
// ---------------------------------------------------------------------------
template <int EPI>
__global__ __launch_bounds__(512, 4)
void gemm_big_bf16(const u16* __restrict__ A, const u16* __restrict__ Bt,
                   const float* __restrict__ bias, void* __restrict__ Cout,
                   int M, int N, int K)
{
    __shared__ __align__(16) u16 As[3 * 8192];   // 3 x 16 KB (256 rows x 32)
    __shared__ __align__(16) u16 Bs[3 * 4096];   // 3 x  8 KB (128 rows x 32)

    const int tid = threadIdx.x;
    const int w = tid >> 6, l = tid & 63;
    const int wm = w >> 1, wn = w & 1;

    const int nbx   = N >> 7;
    const int nwg   = (M >> 8) * nbx;
    const int chunk = nwg >> 3;
    const int wg    = ((int)blockIdx.x & 7) * chunk + ((int)blockIdx.x >> 3);
    const long by   = wg / nbx;
    const long bx   = wg % nbx;

    const int lr  = l >> 2;                      // row within 16-row segment
    const int lsw = (l & 3) ^ ((l >> 3) & 3);    // swizzled source chunk
    const int lg  = l >> 4, lm = l & 15;         // frag k-group / row index
    const int sx  = (lm >> 1) & 3;               // read-side xor key

    const u16* Abase = A  + (size_t)(by * 256) * K;
    const u16* Bbase = Bt + (size_t)(bx * 128) * K;

    f32x4 acc[4][4] = {};

    auto stage = [&](int k0, int b) {
        u16* dA = As + b * 8192;
        u16* dB = Bs + b * 4096;
#pragma unroll
        for (int i = 0; i < 2; ++i) {
            const int seg = w * 2 + i;           // 0..15 -> 16 rows each
            GLD16(Abase + (size_t)(seg * 16 + lr) * K + k0 + lsw * 8,
                  dA + seg * 512);
        }
        GLD16(Bbase + (size_t)(w * 16 + lr) * K + k0 + lsw * 8,
              dB + w * 512);
    };

    const int NT = K >> 5;
    stage(0, 0);
    stage(32, 1);

    int cur = 0, pre = 2;
    for (int t = 0; t < NT; ++t) {
        if (t + 1 < NT) { WAITV3(); } else { WAITV0(); }
        BARRIER();
        if (t + 2 < NT) stage((t + 2) << 5, pre);

        const u16* as = As + cur * 8192;
        const u16* bs = Bs + cur * 4096;
        bf16x8 af[4], bfr[4];
#pragma unroll
        for (int m = 0; m < 4; ++m) {
            const int R = wm * 64 + m * 16 + lm;
            af[m] = *(const bf16x8*)&as[R * 32 + ((lg ^ sx) * 8)];
        }
#pragma unroll
        for (int n = 0; n < 4; ++n) {
            const int R = wn * 64 + n * 16 + lm;
            bfr[n] = *(const bf16x8*)&bs[R * 32 + ((lg ^ sx) * 8)];
        }
#pragma unroll
        for (int m = 0; m < 4; ++m)
#pragma unroll
            for (int n = 0; n < 4; ++n)
                acc[m][n] = __builtin_amdgcn_mfma_f32_16x16x32_bf16(
                    af[m], bfr[n], acc[m][n], 0, 0, 0);

        cur = (cur == 2) ? 0 : cur + 1;
        pre = (pre == 2) ? 0 : pre + 1;
    }

#pragma unroll
    for (int n = 0; n < 4; ++n) {
        const long col = bx * 128 + wn * 64 + n * 16 + lm;
        const float bb = bias[col];
#pragma unroll
        for (int m = 0; m < 4; ++m) {
#pragma unroll
            for (int j = 0; j < 4; ++j) {
                const long row = by * 256 + wm * 64 + m * 16 + lg * 4 + j;
                float e = acc[m][n][j] + bb;
                if (EPI == 1) e = fmaxf(e, 0.f);
                if (EPI == 2) {
                    e = 1.f / (1.f + expf(-e));
                    ((float*)Cout)[row * (long)N + col] = e;
                } else {
                    ((u16*)Cout)[row * (long)N + col] = f2bf(e);
                }
            }
        }
    }
}

// ---------------------------------------------------------------------------
// SMALL-TILE bf16 MFMA GEMM: BM=64, BN=128, BK=32, 256 threads = 4 waves
// (1M x 4N), wave tile 64x32 (acc[4][2]). LDS 3 x 12KB = 36KB -> 4 blocks/CU
// — occupancy-matched for small grids (gemm2: 512 blocks, dec2: 1024).
// Same r8/r9 sync skeleton: 3 buffers, depth-2 prefetch, counted vmcnt(3)
// (3 loads/stage), one raw s_barrier per K-step, both-sides XOR swizzle.
// Per-element K-chain identical (BK=32, one mfma/step, t ascending) ->
// bitwise-same C as the other kernels. T1 XCD remap (nwg % 8 == 0).
// EPI: 0 = bias->bf16, 2 = bias+sigmoid->f32
// ---------------------------------------------------------------------------
template <int EPI>
__global__ __launch_bounds__(256, 4)
void gemm_64_bf16(const u16* __restrict__ A, const u16* __restrict__ Bt,
                  const float* __restrict__ bias, void* __restrict__ Cout,
                  int M, int N, int K)
{
    __shared__ __align__(16) u16 As[3 * 2048];   // 3 x 4 KB (64 rows x 32)
    __shared__ __align__(16) u16 Bs[3 * 4096];   // 3 x 8 KB (128 rows x 32)

    const int tid = threadIdx.x;
    const int w = tid >> 6, l = tid & 63;        // wave = col block (w*32)

    const int nbx   = N >> 7;
    const int nwg   = (M >> 6) * nbx;
    const int chunk = nwg >> 3;
    const int wg    = ((int)blockIdx.x & 7) * chunk + ((int)blockIdx.x >> 3);
    const long by   = wg / nbx;
    const long bx   = wg % nbx;

    const int lr  = l >> 2;
    const int lsw = (l & 3) ^ ((l >> 3) & 3);
    const int lg  = l >> 4, lm = l & 15;
    const int sx  = (lm >> 1) & 3;

    const u16* Abase = A  + (size_t)(by * 64) * K;
    const u16* Bbase = Bt + (size_t)(bx * 128) * K;

    f32x4 acc[4][2] = {};

    auto stage = [&](int k0, int b) {
        u16* dA = As + b * 2048;
        u16* dB = Bs + b * 4096;
        // A: 4 segs of 16 rows, seg = w (1 load/thread)
        GLD16(Abase + (size_t)(w * 16 + lr) * K + k0 + lsw * 8, dA + w * 512);
        // B: 8 segs, seg = w*2+i (2 loads/thread)
#pragma unroll
        for (int i = 0; i < 2; ++i) {
            const int seg = w * 2 + i;
            GLD16(Bbase + (size_t)(seg * 16 + lr) * K + k0 + lsw * 8,
                  dB + seg * 512);
        }
    };

    const int NT = K >> 5;
    stage(0, 0);
    stage(32, 1);

    int cur = 0, pre = 2;
    for (int t = 0; t < NT; ++t) {
        if (t + 1 < NT) { WAITV3(); } else { WAITV0(); }
        BARRIER();
        if (t + 2 < NT) stage((t + 2) << 5, pre);

        const u16* as = As + cur * 2048;
        const u16* bs = Bs + cur * 4096;
        bf16x8 af[4], bfr[2];
#pragma unroll
        for (int m = 0; m < 4; ++m)
            af[m] = *(const bf16x8*)&as[(m * 16 + lm) * 32 + ((lg ^ sx) * 8)];
#pragma unroll
        for (int n = 0; n < 2; ++n) {
            const int R = w * 32 + n * 16 + lm;
            bfr[n] = *(const bf16x8*)&bs[R * 32 + ((lg ^ sx) * 8)];
        }
#pragma unroll
        for (int m = 0; m < 4; ++m)
#pragma unroll
            for (int n = 0; n < 2; ++n)
                acc[m][n] = __builtin_amdgcn_mfma_f32_16x16x32_bf16(
                    af[m], bfr[n], acc[m][n], 0, 0, 0);

        cur = (cur == 2) ? 0 : cur + 1;
        pre = (pre == 2) ? 0 : pre + 1;
    }

    // epilogue: row = by*64 + m*16 + lg*4 + j, col = bx*128 + w*32 + n*16 + lm
#pragma unroll
    for (int n = 0; n < 2; ++n) {
        const long col = bx * 128 + w * 32 + n * 16 + lm;
        const float bb = bias[col];
#pragma unroll
        for (int m = 0; m < 4; ++m) {
#pragma unroll
            for (int j = 0; j < 4; ++j) {
                const long row = by * 64 + m * 16 + lg * 4 + j;
                float e = acc[m][n][j] + bb;
                if (EPI == 2) {
                    e = 1.f / (1.f + expf(-e));
                    ((float*)Cout)[row * (long)N + col] = e;
                } else {
                    ((u16*)Cout)[row * (long)N + col] = f2bf(e);
                }
            }
        }
    }
}

// ---------------------------------------------------------------------------
// VQ phase 1 v2: register-resident A, LDS-streamed codebook (unchanged).
// ---------------------------------------------------------------------------
__global__ __launch_bounds__(256, 2)
void vq_score2(const u16* __restrict__ z, const u16* __restrict__ cbt,
               const float* __restrict__ cn2,
               float* __restrict__ val8, int* __restrict__ idx8)
{
    __shared__ __align__(16) u16 lds[32768];

    const int tid = threadIdx.x;
    const int w = tid >> 6, l = tid & 63;
    const int rq = blockIdx.x >> 3;
    const int q  = blockIdx.x & 7;

    const int st_row8 = tid >> 5;
    const int st_s    = (tid & 31) ^ st_row8;
    const int lg = l >> 4, lm = l & 15;
    const int swz_x = l & 7;

    bf16x8 af[4][8];
    const long zbase_row = (long)rq * 256;
#pragma unroll
    for (int h = 0; h < 2; ++h) {
#pragma unroll
        for (int i = 0; i < 16; ++i) {
            const int row = i * 8 + st_row8;
            const u16* g = z + (zbase_row + h * 128 + row) * DL + st_s * 8;
            GLD16(g, lds + ((size_t)i * 256 + w * 64) * 8);
        }
        __syncthreads();
        if ((w >> 1) == h) {
            const int lrow0 = (w & 1) * 64;
#pragma unroll
            for (int m = 0; m < 4; ++m) {
                const int lrow = lrow0 + m * 16 + lm;
#pragma unroll
                for (int kg = 0; kg < 8; ++kg) {
                    const int s = (kg * 4 + lg) ^ swz_x;
                    af[m][kg] = *(const bf16x8*)&lds[lrow * 256 + s * 8];
                }
            }
        }
        __syncthreads();
    }

    const int code00 = q * (NE / 8);

    float bestv[16];
    int   besti[16];
#pragma unroll
    for (int k = 0; k < 16; ++k) { bestv[k] = 1e30f; besti[k] = 0; }

    auto stage_tile = [&](int t) {
        const int b = t & 1;
#pragma unroll
        for (int i = 0; i < 8; ++i) {
            const int c = i * 8 + st_row8;
            const u16* g = cbt + (size_t)(code00 + t * 64 + c) * DL + st_s * 8;
            GLD16(g, lds + ((size_t)b * 16384 + ((size_t)i * 256 + w * 64) * 8));
        }
    };

    stage_tile(0);
    __syncthreads();

    for (int t = 0; t < 16; ++t) {
        if (t < 15) stage_tile(t + 1);
        const u16* buf = lds + (size_t)(t & 1) * 16384;

#pragma unroll
        for (int n = 0; n < 4; ++n) {
            const int code_g = code00 + t * 64 + n * 16 + lm;
            const float cn2v = cn2[code_g];
            bf16x8 bfr[8];
#pragma unroll
            for (int kg = 0; kg < 8; ++kg) {
                const int lrow = n * 16 + lm;
                const int s = (kg * 4 + lg) ^ swz_x;
                bfr[kg] = *(const bf16x8*)&buf[lrow * 256 + s * 8];
            }
            f32x4 acc[4] = {};
#pragma unroll
            for (int kg = 0; kg < 8; ++kg)
#pragma unroll
                for (int m = 0; m < 4; ++m)
                    acc[m] = __builtin_amdgcn_mfma_f32_16x16x32_bf16(
                        af[m][kg], bfr[kg], acc[m], 0, 0, 0);
#pragma unroll
            for (int m = 0; m < 4; ++m)
#pragma unroll
                for (int j = 0; j < 4; ++j) {
                    const float s = cn2v - acc[m][j];
                    const int k16 = m * 4 + j;
                    if (s < bestv[k16]) { bestv[k16] = s; besti[k16] = code_g; }
                }
        }
        __syncthreads();
    }

#pragma unroll
    for (int off = 1; off < 16; off <<= 1) {
#pragma unroll
        for (int k = 0; k < 16; ++k) {
            const float ov = __shfl_xor(bestv[k], off);
            const int   oi = __shfl_xor(besti[k], off);
            if (ov < bestv[k] || (ov == bestv[k] && oi < besti[k])) {
                bestv[k] = ov; besti[k] = oi;
            }
        }
    }
    if (lm == 0) {
#pragma unroll
        for (int m = 0; m < 4; ++m)
#pragma unroll
            for (int j = 0; j < 4; ++j) {
                const long row = zbase_row + w * 64 + m * 16 + lg * 4 + j;
                val8[(size_t)q * B_ + row] = bestv[m * 4 + j];
                idx8[(size_t)q * B_ + row] = besti[m * 4 + j];
            }
    }
}

// ---------------------------------------------------------------------------
// VQ phase 2: per row pick best of 8 candidates (tie-break lowest idx),
// write final index, accumulate loss partial.
// ---------------------------------------------------------------------------
__global__ __launch_bounds__(256)
void vq_select2(const float* __restrict__ val8, const int* __restrict__ idx8,
                const u16* __restrict__ z, const float* __restrict__ cb,
                int* __restrict__ idxf, float* __restrict__ partial)
{
    __shared__ int   s_idx[256];
    __shared__ float s_red[4];
    const int tid = threadIdx.x;
    const long row = (long)blockIdx.x * 256 + tid;

    float bv = val8[row];
    int   bi = idx8[row];
#pragma unroll
    for (int qq = 1; qq < 8; ++qq) {
        const float v = val8[(size_t)qq * B_ + row];
        const int   i = idx8[(size_t)qq * B_ + row];
        if (v < bv || (v == bv && i < bi)) { bv = v; bi = i; }
    }
    s_idx[tid] = bi;
    idxf[row]  = bi;
    __syncthreads();

    float ls = 0.f;
    const int sub = tid & 7;
#pragma unroll
    for (int pass = 0; pass < 8; ++pass) {
        const int rl = pass * 32 + (tid >> 3);
        const int gi = s_idx[rl];
        const long rg = (long)blockIdx.x * 256 + rl;
#pragma unroll
        for (int tt = 0; tt < 8; ++tt) {
            const int d = sub * 4 + tt * 32;
            float4 c4 = *(const float4*)(cb + (long)gi * DL + d);
            ushort4 zu = *(const ushort4*)(z + rg * DL + d);
            const float dx = c4.x - bf2f(zu.x), dy = c4.y - bf2f(zu.y);
            const float dz = c4.z - bf2f(zu.z), dw = c4.w - bf2f(zu.w);
            ls += dx * dx + dy * dy + dz * dz + dw * dw;
        }
    }
#pragma unroll
    for (int off = 32; off; off >>= 1) ls += __shfl_down(ls, off);
    if ((tid & 63) == 0) s_red[tid >> 6] = ls;
    __syncthreads();
    if (tid == 0)
        partial[blockIdx.x] = s_red[0] + s_red[1] + s_red[2] + s_red[3];
}

// ---------------------------------------------------------------------------
// loss = 1.25 * sum(partial[64]) / (B_*DL)
// ---------------------------------------------------------------------------
__global__ __launch_bounds__(256)
void loss_finalize(const float* __restrict__ partial, float* __restrict__ out)
{
    __shared__ float s_red[4];
    const int tid = threadIdx.x;
    float s = (tid < 64) ? partial[tid] : 0.f;
#pragma unroll
    for (int off = 32; off; off >>= 1) s += __shfl_down(s, off);
    if ((tid & 63) == 0) s_red[tid >> 6] = s;
    __syncthreads();
    if (tid == 0)
        out[0] = 1.25f * (s_red[0] + s_red[1] + s_red[2] + s_red[3])
                 / (float)((long)B_ * DL);
}

// ---------------------------------------------------------------------------
// gather: out[row] = Xcode[idxf[row]]  (1024 f32/row; one wave per row).
// ---------------------------------------------------------------------------
__global__ __launch_bounds__(256)
void gather_rows(const float* __restrict__ Xcode, const int* __restrict__ idxf,
                 float* __restrict__ out)
{
    const int tid  = threadIdx.x;
    const int lane = tid & 63;
    const long row = (long)blockIdx.x * 4 + (tid >> 6);
    const long gi  = idxf[row];
    const float* src = Xcode + gi * DIN;
    float*       dst = out + row * DIN;
#pragma unroll
    for (int t = 0; t < 4; ++t) {
        const int d = lane * 4 + t * 256;
        *(float4*)(dst + d) = *(const float4*)(src + d);
    }
}

// ---------------------------------------------------------------------------
extern "C" void kernel_launch(void* const* d_in, const int* in_sizes, int n_in,
                              void* d_out, int out_size, void* d_ws, size_t ws_size,
                              hipStream_t stream)
{
    const float* x   = (const float*)d_in[0];
    const float* ew1 = (const float*)d_in[1];
    const float* eb1 = (const float*)d_in[2];
    const float* ew2 = (const float*)d_in[3];
    const float* eb2 = (const float*)d_in[4];
    const float* cbk = (const float*)d_in[5];
    const float* dw1 = (const float*)d_in[6];
    const float* db1 = (const float*)d_in[7];
    const float* dw2 = (const float*)d_in[8];
    const float* db2 = (const float*)d_in[9];
    float* out = (float*)d_out;

    char* p = (char*)d_ws;
    auto alloc = [&](size_t bytes) {
        char* r = p; p += (bytes + 255) & ~(size_t)255; return r;
    };
    u16*   x_bf  = (u16*)alloc((size_t)B_ * DIN * 2);
    u16*   h_bf  = (u16*)alloc((size_t)B_ * DH * 2);   // encoder h; then Hcode
    u16*   z_bf  = (u16*)alloc((size_t)B_ * DL * 2);
    u16*   cb_bf = (u16*)alloc((size_t)NE * DL * 2);
    u16*   w1t   = (u16*)alloc((size_t)DH * DIN * 2);  // [N][K] bf16
    u16*   w2t   = (u16*)alloc((size_t)DL * DH * 2);
    u16*   wd1t  = (u16*)alloc((size_t)DH * DL * 2);
    u16*   wd2t  = (u16*)alloc((size_t)DIN * DH * 2);
    float* Xcode = (float*)alloc((size_t)NE * DIN * 4);   // per-code recon
    float* cn2   = (float*)alloc((size_t)NE * 4);
    float* val8  = (float*)alloc((size_t)8 * B_ * 4);
    int*   idx8  = (int*)alloc((size_t)8 * B_ * 4);
    int*   idxf  = (int*)alloc((size_t)B_ * 4);
    float* part  = (float*)alloc(64 * 4);

    // fused prologue: casts, weight transposes, cn2 (one launch)
    prep_fused<<<25600, 256, 0, stream>>>(x, x_bf, cbk, cb_bf,
                                          ew1, w1t, ew2, w2t,
                                          dw1, wd1t, dw2, wd2t, cn2);

    // encoder
    gemm_big_bf16<1><<<(B_ / 256) * (DH / 128), 512, 0, stream>>>(
        x_bf, w1t, eb1, h_bf, B_, DH, DIN);
    gemm_64_bf16<0><<<(B_ / 64) * (DL / 128), 256, 0, stream>>>(
        h_bf, w2t, eb2, z_bf, B_, DL, DH);

    // vector quantizer -> final index per row + loss
    vq_score2<<<512, 256, 0, stream>>>(z_bf, cb_bf, cn2, val8, idx8);
    vq_select2<<<B_ / 256, 256, 0, stream>>>(val8, idx8, z_bf, cbk, idxf, part);
    loss_finalize<<<1, 256, 0, stream>>>(part, out + (size_t)B_ * DIN);

    // decoder per CODE (8192 rows), then gather rows by index.
    gemm_big_bf16<1><<<(NE / 256) * (DH / 128), 512, 0, stream>>>(
        cb_bf, wd1t, db1, h_bf, NE, DH, DL);
    gemm_64_bf16<2><<<(NE / 64) * (DIN / 128), 256, 0, stream>>>(
        h_bf, wd2t, db2, Xcode, NE, DIN, DH);
    gather_rows<<<B_ / 4, 256, 0, stream>>>(Xcode, idxf, out);
}

// Round 14
// 294.020 us; speedup vs baseline: 1.1694x; 1.0212x over previous
//
#include <hip/hip_runtime.h>
#include <math.h>

typedef unsigned short u16;
typedef __bf16 bf16x8 __attribute__((ext_vector_type(8)));
typedef float  f32x4  __attribute__((ext_vector_type(4)));

constexpr int B_  = 16384;   // batch
constexpr int DIN = 1024;    // input dim
constexpr int DH  = 2048;    // hidden dim
constexpr int DL  = 256;     // latent dim
constexpr int NE  = 8192;    // codebook entries

__device__ __forceinline__ u16 f2bf(float f) {     // RTNE float->bf16
    union { float f; unsigned u; } v; v.f = f;
    unsigned r = v.u + 0x7fffu + ((v.u >> 16) & 1u);
    return (u16)(r >> 16);
}
__device__ __forceinline__ float bf2f(u16 h) {
    union { unsigned u; float f; } v; v.u = ((unsigned)h) << 16;
    return v.f;
}

#define GLD16(gp, lp)                                                  \
    __builtin_amdgcn_global_load_lds(                                  \
        (__attribute__((address_space(1))) void*)(gp),                 \
        (__attribute__((address_space(3))) void*)(lp), 16, 0, 0)

#define SCHED0() __builtin_amdgcn_sched_barrier(0)
#define BARRIER() do { SCHED0(); __builtin_amdgcn_s_barrier(); SCHED0(); } while (0)
#define WAITV0() asm volatile("s_waitcnt vmcnt(0)" ::: "memory")
#define WAITV3() asm volatile("s_waitcnt vmcnt(3)" ::: "memory")

// ---------------------------------------------------------------------------
// Fused prologue: one launch (2 casts, 4 transpose-casts, cn2) — r12-proven.
// ---------------------------------------------------------------------------
__device__ __forceinline__ void dev_cast(const float* __restrict__ in,
                                         u16* __restrict__ out, long blk)
{
    const size_t i = ((size_t)blk * 256 + threadIdx.x) * 4;
    float4 v = *(const float4*)(in + i);
    ushort4 o;
    o.x = f2bf(v.x); o.y = f2bf(v.y); o.z = f2bf(v.z); o.w = f2bf(v.w);
    *(ushort4*)(out + i) = o;
}

__device__ __forceinline__ void dev_transpose(const float* __restrict__ in,
                                              u16* __restrict__ out,
                                              int R, int C, long bx, long by,
                                              float (*t)[33])
{
    const int tx = threadIdx.x & 31, ty = threadIdx.x >> 5;
#pragma unroll
    for (int p = 0; p < 4; ++p)
        t[ty + p * 8][tx] = in[(by * 32 + ty + p * 8) * (long)C + bx * 32 + tx];
    __syncthreads();
#pragma unroll
    for (int p = 0; p < 4; ++p)
        out[(bx * 32 + ty + p * 8) * (long)R + by * 32 + tx] = f2bf(t[tx][ty + p * 8]);
}

__global__ __launch_bounds__(256)
void prep_fused(const float* __restrict__ x,   u16* __restrict__ x_bf,
                const float* __restrict__ cb,  u16* __restrict__ cb_bf,
                const float* __restrict__ ew1, u16* __restrict__ w1t,
                const float* __restrict__ ew2, u16* __restrict__ w2t,
                const float* __restrict__ dw1, u16* __restrict__ wd1t,
                const float* __restrict__ dw2, u16* __restrict__ wd2t,
                float* __restrict__ cn2)
{
    __shared__ float t[32][33];
    const long b = blockIdx.x;

    if (b < 16384) {                       // cast x
        dev_cast(x, x_bf, b);
    } else if (b < 18432) {                // cast cb
        dev_cast(cb, cb_bf, b - 16384);
    } else if (b < 20480) {                // ew1 [1024,2048] -> w1t, gx=64
        const long r = b - 18432;
        dev_transpose(ew1, w1t, DIN, DH, r % 64, r / 64, t);
    } else if (b < 20992) {                // ew2 [2048,256] -> w2t, gx=8
        const long r = b - 20480;
        dev_transpose(ew2, w2t, DH, DL, r % 8, r / 8, t);
    } else if (b < 21504) {                // dw1 [256,2048] -> wd1t, gx=64
        const long r = b - 20992;
        dev_transpose(dw1, wd1t, DL, DH, r % 64, r / 64, t);
    } else if (b < 23552) {                // dw2 [2048,1024] -> wd2t, gx=32
        const long r = b - 21504;
        dev_transpose(dw2, wd2t, DH, DIN, r % 32, r / 32, t);
    } else {                               // cn2: 4 codes/block
        const long r = b - 23552;
        const int code = (int)((r * 256 + threadIdx.x) >> 6);
        const int lane = threadIdx.x & 63;
        float4 v = *(const float4*)(cb + (long)code * DL + lane * 4);
        float s = fmaf(v.x, v.x, fmaf(v.y, v.y, fmaf(v.z, v.z, v.w * v.w)));
#pragma unroll
        for (int off = 32; off; off >>= 1) s += __shfl_down(s, off);
        if (lane == 0) cn2[code] = 0.5f * s;
    }
}

// ---------------------------------------------------------------------------
// BIG bf16 MFMA GEMM (r9-proven): BM=256, BN=128, BK=32, 512 threads =
// 8 waves (4M x 2N). T4 counted-vmcnt, 3 LDS buffers (72KB, 2 blocks/CU),
// depth-2 prefetch, one raw s_barrier per K-step, both-sides XOR swizzle,
// T1 XCD remap. Used for gemm1 (grid 2048).
// EPI: 1 = bias+relu->bf16
// ---------------------------------------------------------------------------
template <int EPI>
__global__ __launch_bounds__(512, 4)
void gemm_big_bf16(const u16* __restrict__ A, const u16* __restrict__ Bt,
                   const float* __restrict__ bias, void* __restrict__ Cout,
                   int M, int N, int K)
{
    __shared__ __align__(16) u16 As[3 * 8192];   // 3 x 16 KB (256 rows x 32)
    __shared__ __align__(16) u16 Bs[3 * 4096];   // 3 x  8 KB (128 rows x 32)

    const int tid = threadIdx.x;
    const int w = tid >> 6, l = tid & 63;
    const int wm = w >> 1, wn = w & 1;

    const int nbx   = N >> 7;
    const int nwg   = (M >> 8) * nbx;
    const int chunk = nwg >> 3;
    const int wg    = ((int)blockIdx.x & 7) * chunk + ((int)blockIdx.x >> 3);
    const long by   = wg / nbx;
    const long bx   = wg % nbx;

    const int lr  = l >> 2;                      // row within 16-row segment
    const int lsw = (l & 3) ^ ((l >> 3) & 3);    // swizzled source chunk
    const int lg  = l >> 4, lm = l & 15;         // frag k-group / row index
    const int sx  = (lm >> 1) & 3;               // read-side xor key

    const u16* Abase = A  + (size_t)(by * 256) * K;
    const u16* Bbase = Bt + (size_t)(bx * 128) * K;

    f32x4 acc[4][4] = {};

    auto stage = [&](int k0, int b) {
        u16* dA = As + b * 8192;
        u16* dB = Bs + b * 4096;
#pragma unroll
        for (int i = 0; i < 2; ++i) {
            const int seg = w * 2 + i;           // 0..15 -> 16 rows each
            GLD16(Abase + (size_t)(seg * 16 + lr) * K + k0 + lsw * 8,
                  dA + seg * 512);
        }
        GLD16(Bbase + (size_t)(w * 16 + lr) * K + k0 + lsw * 8,
              dB + w * 512);
    };

    const int NT = K >> 5;
    stage(0, 0);
    stage(32, 1);

    int cur = 0, pre = 2;
    for (int t = 0; t < NT; ++t) {
        if (t + 1 < NT) { WAITV3(); } else { WAITV0(); }
        BARRIER();
        if (t + 2 < NT) stage((t + 2) << 5, pre);

        const u16* as = As + cur * 8192;
        const u16* bs = Bs + cur * 4096;
        bf16x8 af[4], bfr[4];
#pragma unroll
        for (int m = 0; m < 4; ++m) {
            const int R = wm * 64 + m * 16 + lm;
            af[m] = *(const bf16x8*)&as[R * 32 + ((lg ^ sx) * 8)];
        }
#pragma unroll
        for (int n = 0; n < 4; ++n) {
            const int R = wn * 64 + n * 16 + lm;
            bfr[n] = *(const bf16x8*)&bs[R * 32 + ((lg ^ sx) * 8)];
        }
#pragma unroll
        for (int m = 0; m < 4; ++m)
#pragma unroll
            for (int n = 0; n < 4; ++n)
                acc[m][n] = __builtin_amdgcn_mfma_f32_16x16x32_bf16(
                    af[m], bfr[n], acc[m][n], 0, 0, 0);

        cur = (cur == 2) ? 0 : cur + 1;
        pre = (pre == 2) ? 0 : pre + 1;
    }

#pragma unroll
    for (int n = 0; n < 4; ++n) {
        const long col = bx * 128 + wn * 64 + n * 16 + lm;
        const float bb = bias[col];
#pragma unroll
        for (int m = 0; m < 4; ++m) {
#pragma unroll
            for (int j = 0; j < 4; ++j) {
                const long row = by * 256 + wm * 64 + m * 16 + lg * 4 + j;
                float e = acc[m][n][j] + bb;
                if (EPI == 1) e = fmaxf(e, 0.f);
                ((u16*)Cout)[row * (long)N + col] = f2bf(e);
            }
        }
    }
}

// ---------------------------------------------------------------------------
// SMALL-TILE core: BM=64, BN=128, BK=32, 256 threads = 4 waves (1M x 4N),
// wave tile 64x32 (acc[4][2]). LDS 3x(4+8)KB = 36KB -> 4 blocks/CU.
// r8/r9 sync skeleton: 3 buffers, depth-2 prefetch, counted vmcnt(3),
// one raw s_barrier per K-step, both-sides XOR swizzle, T1 XCD remap.
// Per-element K-chain identical to the other kernels -> bitwise-same C.
// epi (runtime, block-uniform): 0 = bias->bf16, 1 = +relu->bf16,
// 2 = +sigmoid->f32.
// ---------------------------------------------------------------------------
__device__ __forceinline__ void gemm64_core(
    const u16* __restrict__ A, const u16* __restrict__ Bt,
    const float* __restrict__ bias, void* __restrict__ Cout,
    int M, int N, int K, int epi, int bid,
    u16* __restrict__ As, u16* __restrict__ Bs)
{
    const int tid = threadIdx.x;
    const int w = tid >> 6, l = tid & 63;        // wave = col block (w*32)

    const int nbx   = N >> 7;
    const int nwg   = (M >> 6) * nbx;
    const int chunk = nwg >> 3;
    const int wg    = (bid & 7) * chunk + (bid >> 3);
    const long by   = wg / nbx;
    const long bx   = wg % nbx;

    const int lr  = l >> 2;
    const int lsw = (l & 3) ^ ((l >> 3) & 3);
    const int lg  = l >> 4, lm = l & 15;
    const int sx  = (lm >> 1) & 3;

    const u16* Abase = A  + (size_t)(by * 64) * K;
    const u16* Bbase = Bt + (size_t)(bx * 128) * K;

    f32x4 acc[4][2] = {};

    auto stage = [&](int k0, int b) {
        u16* dA = As + b * 2048;
        u16* dB = Bs + b * 4096;
        GLD16(Abase + (size_t)(w * 16 + lr) * K + k0 + lsw * 8, dA + w * 512);
#pragma unroll
        for (int i = 0; i < 2; ++i) {
            const int seg = w * 2 + i;
            GLD16(Bbase + (size_t)(seg * 16 + lr) * K + k0 + lsw * 8,
                  dB + seg * 512);
        }
    };

    const int NT = K >> 5;
    stage(0, 0);
    stage(32, 1);

    int cur = 0, pre = 2;
    for (int t = 0; t < NT; ++t) {
        if (t + 1 < NT) { WAITV3(); } else { WAITV0(); }
        BARRIER();
        if (t + 2 < NT) stage((t + 2) << 5, pre);

        const u16* as = As + cur * 2048;
        const u16* bs = Bs + cur * 4096;
        bf16x8 af[4], bfr[2];
#pragma unroll
        for (int m = 0; m < 4; ++m)
            af[m] = *(const bf16x8*)&as[(m * 16 + lm) * 32 + ((lg ^ sx) * 8)];
#pragma unroll
        for (int n = 0; n < 2; ++n) {
            const int R = w * 32 + n * 16 + lm;
            bfr[n] = *(const bf16x8*)&bs[R * 32 + ((lg ^ sx) * 8)];
        }
#pragma unroll
        for (int m = 0; m < 4; ++m)
#pragma unroll
            for (int n = 0; n < 2; ++n)
                acc[m][n] = __builtin_amdgcn_mfma_f32_16x16x32_bf16(
                    af[m], bfr[n], acc[m][n], 0, 0, 0);

        cur = (cur == 2) ? 0 : cur + 1;
        pre = (pre == 2) ? 0 : pre + 1;
    }

    // epilogue: row = by*64 + m*16 + lg*4 + j, col = bx*128 + w*32 + n*16 + lm
#pragma unroll
    for (int n = 0; n < 2; ++n) {
        const long col = bx * 128 + w * 32 + n * 16 + lm;
        const float bb = bias[col];
#pragma unroll
        for (int m = 0; m < 4; ++m) {
#pragma unroll
            for (int j = 0; j < 4; ++j) {
                const long row = by * 64 + m * 16 + lg * 4 + j;
                float e = acc[m][n][j] + bb;
                if (epi == 1) e = fmaxf(e, 0.f);
                if (epi == 2) {
                    e = 1.f / (1.f + expf(-e));
                    ((float*)Cout)[row * (long)N + col] = e;
                } else {
                    ((u16*)Cout)[row * (long)N + col] = f2bf(e);
                }
            }
        }
    }
}

// ---------------------------------------------------------------------------
// Fused: gemm2 (encoder z) + dec1 (per-code decoder hidden) — independent
// work, one launch. Blocks [0,512): z = h @ w2t + eb2 (bf16).
// Blocks [512,2560): Hcode = relu(cb @ wd1t + db1) (bf16, into x_bf which
// is dead after gemm1). Branch is block-uniform -> barriers safe.
// ---------------------------------------------------------------------------
__global__ __launch_bounds__(256, 4)
void gemm2_dec1_fused(const u16* __restrict__ h,  const u16* __restrict__ w2t,
                      const float* __restrict__ eb2, u16* __restrict__ z,
                      const u16* __restrict__ cb, const u16* __restrict__ wd1t,
                      const float* __restrict__ db1, u16* __restrict__ hcode)
{
    __shared__ __align__(16) u16 As[3 * 2048];
    __shared__ __align__(16) u16 Bs[3 * 4096];
    const int b = (int)blockIdx.x;
    if (b < 512)
        gemm64_core(h, w2t, eb2, z, B_, DL, DH, 0, b, As, Bs);
    else
        gemm64_core(cb, wd1t, db1, hcode, NE, DH, DL, 1, b - 512, As, Bs);
}

// ---------------------------------------------------------------------------
// dec2: Xcode = sigmoid(Hcode @ wd2t + db2) (f32), 1024 blocks.
// ---------------------------------------------------------------------------
__global__ __launch_bounds__(256, 4)
void gemm_dec2(const u16* __restrict__ hcode, const u16* __restrict__ wd2t,
               const float* __restrict__ db2, float* __restrict__ Xcode)
{
    __shared__ __align__(16) u16 As[3 * 2048];
    __shared__ __align__(16) u16 Bs[3 * 4096];
    gemm64_core(hcode, wd2t, db2, Xcode, NE, DIN, DH, 2, (int)blockIdx.x, As, Bs);
}

// ---------------------------------------------------------------------------
// VQ phase 1 v2: register-resident A, LDS-streamed codebook (unchanged).
// ---------------------------------------------------------------------------
__global__ __launch_bounds__(256, 2)
void vq_score2(const u16* __restrict__ z, const u16* __restrict__ cbt,
               const float* __restrict__ cn2,
               float* __restrict__ val8, int* __restrict__ idx8)
{
    __shared__ __align__(16) u16 lds[32768];

    const int tid = threadIdx.x;
    const int w = tid >> 6, l = tid & 63;
    const int rq = blockIdx.x >> 3;
    const int q  = blockIdx.x & 7;

    const int st_row8 = tid >> 5;
    const int st_s    = (tid & 31) ^ st_row8;
    const int lg = l >> 4, lm = l & 15;
    const int swz_x = l & 7;

    bf16x8 af[4][8];
    const long zbase_row = (long)rq * 256;
#pragma unroll
    for (int h = 0; h < 2; ++h) {
#pragma unroll
        for (int i = 0; i < 16; ++i) {
            const int row = i * 8 + st_row8;
            const u16* g = z + (zbase_row + h * 128 + row) * DL + st_s * 8;
            GLD16(g, lds + ((size_t)i * 256 + w * 64) * 8);
        }
        __syncthreads();
        if ((w >> 1) == h) {
            const int lrow0 = (w & 1) * 64;
#pragma unroll
            for (int m = 0; m < 4; ++m) {
                const int lrow = lrow0 + m * 16 + lm;
#pragma unroll
                for (int kg = 0; kg < 8; ++kg) {
                    const int s = (kg * 4 + lg) ^ swz_x;
                    af[m][kg] = *(const bf16x8*)&lds[lrow * 256 + s * 8];
                }
            }
        }
        __syncthreads();
    }

    const int code00 = q * (NE / 8);

    float bestv[16];
    int   besti[16];
#pragma unroll
    for (int k = 0; k < 16; ++k) { bestv[k] = 1e30f; besti[k] = 0; }

    auto stage_tile = [&](int t) {
        const int b = t & 1;
#pragma unroll
        for (int i = 0; i < 8; ++i) {
            const int c = i * 8 + st_row8;
            const u16* g = cbt + (size_t)(code00 + t * 64 + c) * DL + st_s * 8;
            GLD16(g, lds + ((size_t)b * 16384 + ((size_t)i * 256 + w * 64) * 8));
        }
    };

    stage_tile(0);
    __syncthreads();

    for (int t = 0; t < 16; ++t) {
        if (t < 15) stage_tile(t + 1);
        const u16* buf = lds + (size_t)(t & 1) * 16384;

#pragma unroll
        for (int n = 0; n < 4; ++n) {
            const int code_g = code00 + t * 64 + n * 16 + lm;
            const float cn2v = cn2[code_g];
            bf16x8 bfr[8];
#pragma unroll
            for (int kg = 0; kg < 8; ++kg) {
                const int lrow = n * 16 + lm;
                const int s = (kg * 4 + lg) ^ swz_x;
                bfr[kg] = *(const bf16x8*)&buf[lrow * 256 + s * 8];
            }
            f32x4 acc[4] = {};
#pragma unroll
            for (int kg = 0; kg < 8; ++kg)
#pragma unroll
                for (int m = 0; m < 4; ++m)
                    acc[m] = __builtin_amdgcn_mfma_f32_16x16x32_bf16(
                        af[m][kg], bfr[kg], acc[m], 0, 0, 0);
#pragma unroll
            for (int m = 0; m < 4; ++m)
#pragma unroll
                for (int j = 0; j < 4; ++j) {
                    const float s = cn2v - acc[m][j];
                    const int k16 = m * 4 + j;
                    if (s < bestv[k16]) { bestv[k16] = s; besti[k16] = code_g; }
                }
        }
        __syncthreads();
    }

#pragma unroll
    for (int off = 1; off < 16; off <<= 1) {
#pragma unroll
        for (int k = 0; k < 16; ++k) {
            const float ov = __shfl_xor(bestv[k], off);
            const int   oi = __shfl_xor(besti[k], off);
            if (ov < bestv[k] || (ov == bestv[k] && oi < besti[k])) {
                bestv[k] = ov; besti[k] = oi;
            }
        }
    }
    if (lm == 0) {
#pragma unroll
        for (int m = 0; m < 4; ++m)
#pragma unroll
            for (int j = 0; j < 4; ++j) {
                const long row = zbase_row + w * 64 + m * 16 + lg * 4 + j;
                val8[(size_t)q * B_ + row] = bestv[m * 4 + j];
                idx8[(size_t)q * B_ + row] = besti[m * 4 + j];
            }
    }
}

// ---------------------------------------------------------------------------
// VQ phase 2: per row pick best of 8 candidates (tie-break lowest idx),
// write final index, accumulate loss partial.
// ---------------------------------------------------------------------------
__global__ __launch_bounds__(256)
void vq_select2(const float* __restrict__ val8, const int* __restrict__ idx8,
                const u16* __restrict__ z, const float* __restrict__ cb,
                int* __restrict__ idxf, float* __restrict__ partial)
{
    __shared__ int   s_idx[256];
    __shared__ float s_red[4];
    const int tid = threadIdx.x;
    const long row = (long)blockIdx.x * 256 + tid;

    float bv = val8[row];
    int   bi = idx8[row];
#pragma unroll
    for (int qq = 1; qq < 8; ++qq) {
        const float v = val8[(size_t)qq * B_ + row];
        const int   i = idx8[(size_t)qq * B_ + row];
        if (v < bv || (v == bv && i < bi)) { bv = v; bi = i; }
    }
    s_idx[tid] = bi;
    idxf[row]  = bi;
    __syncthreads();

    float ls = 0.f;
    const int sub = tid & 7;
#pragma unroll
    for (int pass = 0; pass < 8; ++pass) {
        const int rl = pass * 32 + (tid >> 3);
        const int gi = s_idx[rl];
        const long rg = (long)blockIdx.x * 256 + rl;
#pragma unroll
        for (int tt = 0; tt < 8; ++tt) {
            const int d = sub * 4 + tt * 32;
            float4 c4 = *(const float4*)(cb + (long)gi * DL + d);
            ushort4 zu = *(const ushort4*)(z + rg * DL + d);
            const float dx = c4.x - bf2f(zu.x), dy = c4.y - bf2f(zu.y);
            const float dz = c4.z - bf2f(zu.z), dw = c4.w - bf2f(zu.w);
            ls += dx * dx + dy * dy + dz * dz + dw * dw;
        }
    }
#pragma unroll
    for (int off = 32; off; off >>= 1) ls += __shfl_down(ls, off);
    if ((tid & 63) == 0) s_red[tid >> 6] = ls;
    __syncthreads();
    if (tid == 0)
        partial[blockIdx.x] = s_red[0] + s_red[1] + s_red[2] + s_red[3];
}

// ---------------------------------------------------------------------------
// loss = 1.25 * sum(partial[64]) / (B_*DL)
// ---------------------------------------------------------------------------
__global__ __launch_bounds__(256)
void loss_finalize(const float* __restrict__ partial, float* __restrict__ out)
{
    __shared__ float s_red[4];
    const int tid = threadIdx.x;
    float s = (tid < 64) ? partial[tid] : 0.f;
#pragma unroll
    for (int off = 32; off; off >>= 1) s += __shfl_down(s, off);
    if ((tid & 63) == 0) s_red[tid >> 6] = s;
    __syncthreads();
    if (tid == 0)
        out[0] = 1.25f * (s_red[0] + s_red[1] + s_red[2] + s_red[3])
                 / (float)((long)B_ * DL);
}

// ---------------------------------------------------------------------------
// gather: out[row] = Xcode[idxf[row]]  (1024 f32/row; one wave per row).
// ---------------------------------------------------------------------------
__global__ __launch_bounds__(256)
void gather_rows(const float* __restrict__ Xcode, const int* __restrict__ idxf,
                 float* __restrict__ out)
{
    const int tid  = threadIdx.x;
    const int lane = tid & 63;
    const long row = (long)blockIdx.x * 4 + (tid >> 6);
    const long gi  = idxf[row];
    const float* src = Xcode + gi * DIN;
    float*       dst = out + row * DIN;
#pragma unroll
    for (int t = 0; t < 4; ++t) {
        const int d = lane * 4 + t * 256;
        *(float4*)(dst + d) = *(const float4*)(src + d);
    }
}

// ---------------------------------------------------------------------------
extern "C" void kernel_launch(void* const* d_in, const int* in_sizes, int n_in,
                              void* d_out, int out_size, void* d_ws, size_t ws_size,
                              hipStream_t stream)
{
    const float* x   = (const float*)d_in[0];
    const float* ew1 = (const float*)d_in[1];
    const float* eb1 = (const float*)d_in[2];
    const float* ew2 = (const float*)d_in[3];
    const float* eb2 = (const float*)d_in[4];
    const float* cbk = (const float*)d_in[5];
    const float* dw1 = (const float*)d_in[6];
    const float* db1 = (const float*)d_in[7];
    const float* dw2 = (const float*)d_in[8];
    const float* db2 = (const float*)d_in[9];
    float* out = (float*)d_out;

    char* p = (char*)d_ws;
    auto alloc = [&](size_t bytes) {
        char* r = p; p += (bytes + 255) & ~(size_t)255; return r;
    };
    u16*   x_bf  = (u16*)alloc((size_t)B_ * DIN * 2);  // x; later Hcode [NE,DH]
    u16*   h_bf  = (u16*)alloc((size_t)B_ * DH * 2);   // encoder h
    u16*   z_bf  = (u16*)alloc((size_t)B_ * DL * 2);
    u16*   cb_bf = (u16*)alloc((size_t)NE * DL * 2);
    u16*   w1t   = (u16*)alloc((size_t)DH * DIN * 2);  // [N][K] bf16
    u16*   w2t   = (u16*)alloc((size_t)DL * DH * 2);
    u16*   wd1t  = (u16*)alloc((size_t)DH * DL * 2);
    u16*   wd2t  = (u16*)alloc((size_t)DIN * DH * 2);
    float* Xcode = (float*)alloc((size_t)NE * DIN * 4);   // per-code recon
    float* cn2   = (float*)alloc((size_t)NE * 4);
    float* val8  = (float*)alloc((size_t)8 * B_ * 4);
    int*   idx8  = (int*)alloc((size_t)8 * B_ * 4);
    int*   idxf  = (int*)alloc((size_t)B_ * 4);
    float* part  = (float*)alloc(64 * 4);

    u16* hcode = x_bf;   // [NE, DH] bf16 = 32 MiB, exact overlay; x_bf dead
                         // after gemm1, hcode written only in the fused launch

    // fused prologue: casts, weight transposes, cn2 (one launch)
    prep_fused<<<25600, 256, 0, stream>>>(x, x_bf, cbk, cb_bf,
                                          ew1, w1t, ew2, w2t,
                                          dw1, wd1t, dw2, wd2t, cn2);

    // encoder GEMM1 (reads x_bf -- last reader before hcode overlay)
    gemm_big_bf16<1><<<(B_ / 256) * (DH / 128), 512, 0, stream>>>(
        x_bf, w1t, eb1, h_bf, B_, DH, DIN);

    // fused: encoder GEMM2 (512 blocks) + decoder dec1 (2048 blocks)
    gemm2_dec1_fused<<<2560, 256, 0, stream>>>(h_bf, w2t, eb2, z_bf,
                                               cb_bf, wd1t, db1, hcode);

    // decoder dec2 (per-code recon), independent of VQ chain below
    gemm_dec2<<<(NE / 64) * (DIN / 128), 256, 0, stream>>>(
        hcode, wd2t, db2, Xcode);

    // vector quantizer -> final index per row + loss
    vq_score2<<<512, 256, 0, stream>>>(z_bf, cb_bf, cn2, val8, idx8);
    vq_select2<<<B_ / 256, 256, 0, stream>>>(val8, idx8, z_bf, cbk, idxf, part);
    loss_finalize<<<1, 256, 0, stream>>>(part, out + (size_t)B_ * DIN);

    // final gather
    gather_rows<<<B_ / 4, 256, 0, stream>>>(Xcode, idxf, out);
}

// Round 15
// 292.684 us; speedup vs baseline: 1.1747x; 1.0046x over previous
//
#include <hip/hip_runtime.h>
#include <math.h>

typedef unsigned short u16;
typedef __bf16 bf16x8 __attribute__((ext_vector_type(8)));
typedef float  f32x4  __attribute__((ext_vector_type(4)));

constexpr int B_  = 16384;   // batch
constexpr int DIN = 1024;    // input dim
constexpr int DH  = 2048;    // hidden dim
constexpr int DL  = 256;     // latent dim
constexpr int NE  = 8192;    // codebook entries

__device__ __forceinline__ u16 f2bf(float f) {     // RTNE float->bf16
    union { float f; unsigned u; } v; v.f = f;
    unsigned r = v.u + 0x7fffu + ((v.u >> 16) & 1u);
    return (u16)(r >> 16);
}
__device__ __forceinline__ float bf2f(u16 h) {
    union { unsigned u; float f; } v; v.u = ((unsigned)h) << 16;
    return v.f;
}

#define GLD16(gp, lp)                                                  \
    __builtin_amdgcn_global_load_lds(                                  \
        (__attribute__((address_space(1))) void*)(gp),                 \
        (__attribute__((address_space(3))) void*)(lp), 16, 0, 0)

#define SCHED0() __builtin_amdgcn_sched_barrier(0)
#define BARRIER() do { SCHED0(); __builtin_amdgcn_s_barrier(); SCHED0(); } while (0)
#define WAITV0() asm volatile("s_waitcnt vmcnt(0)" ::: "memory")
#define WAITV3() asm volatile("s_waitcnt vmcnt(3)" ::: "memory")
#define WAITV4() asm volatile("s_waitcnt vmcnt(4)" ::: "memory")

// ---------------------------------------------------------------------------
// Fused prologue: one launch (2 casts, 4 transpose-casts, cn2) — r12-proven.
// ---------------------------------------------------------------------------
__device__ __forceinline__ void dev_cast(const float* __restrict__ in,
                                         u16* __restrict__ out, long blk)
{
    const size_t i = ((size_t)blk * 256 + threadIdx.x) * 4;
    float4 v = *(const float4*)(in + i);
    ushort4 o;
    o.x = f2bf(v.x); o.y = f2bf(v.y); o.z = f2bf(v.z); o.w = f2bf(v.w);
    *(ushort4*)(out + i) = o;
}

__device__ __forceinline__ void dev_transpose(const float* __restrict__ in,
                                              u16* __restrict__ out,
                                              int R, int C, long bx, long by,
                                              float (*t)[33])
{
    const int tx = threadIdx.x & 31, ty = threadIdx.x >> 5;
#pragma unroll
    for (int p = 0; p < 4; ++p)
        t[ty + p * 8][tx] = in[(by * 32 + ty + p * 8) * (long)C + bx * 32 + tx];
    __syncthreads();
#pragma unroll
    for (int p = 0; p < 4; ++p)
        out[(bx * 32 + ty + p * 8) * (long)R + by * 32 + tx] = f2bf(t[tx][ty + p * 8]);
}

__global__ __launch_bounds__(256)
void prep_fused(const float* __restrict__ x,   u16* __restrict__ x_bf,
                const float* __restrict__ cb,  u16* __restrict__ cb_bf,
                const float* __restrict__ ew1, u16* __restrict__ w1t,
                const float* __restrict__ ew2, u16* __restrict__ w2t,
                const float* __restrict__ dw1, u16* __restrict__ wd1t,
                const float* __restrict__ dw2, u16* __restrict__ wd2t,
                float* __restrict__ cn2)
{
    __shared__ float t[32][33];
    const long b = blockIdx.x;

    if (b < 16384) {                       // cast x
        dev_cast(x, x_bf, b);
    } else if (b < 18432) {                // cast cb
        dev_cast(cb, cb_bf, b - 16384);
    } else if (b < 20480) {                // ew1 [1024,2048] -> w1t, gx=64
        const long r = b - 18432;
        dev_transpose(ew1, w1t, DIN, DH, r % 64, r / 64, t);
    } else if (b < 20992) {                // ew2 [2048,256] -> w2t, gx=8
        const long r = b - 20480;
        dev_transpose(ew2, w2t, DH, DL, r % 8, r / 8, t);
    } else if (b < 21504) {                // dw1 [256,2048] -> wd1t, gx=64
        const long r = b - 20992;
        dev_transpose(dw1, wd1t, DL, DH, r % 64, r / 64, t);
    } else if (b < 23552) {                // dw2 [2048,1024] -> wd2t, gx=32
        const long r = b - 21504;
        dev_transpose(dw2, wd2t, DH, DIN, r % 32, r / 32, t);
    } else {                               // cn2: 4 codes/block
        const long r = b - 23552;
        const int code = (int)((r * 256 + threadIdx.x) >> 6);
        const int lane = threadIdx.x & 63;
        float4 v = *(const float4*)(cb + (long)code * DL + lane * 4);
        float s = fmaf(v.x, v.x, fmaf(v.y, v.y, fmaf(v.z, v.z, v.w * v.w)));
#pragma unroll
        for (int off = 32; off; off >>= 1) s += __shfl_down(s, off);
        if (lane == 0) cn2[code] = 0.5f * s;
    }
}

// ---------------------------------------------------------------------------
// BIG bf16 MFMA GEMM (r9-proven): BM=256, BN=128, BK=32, 512 threads =
// 8 waves (4M x 2N). T4 counted-vmcnt, 3 LDS buffers (72KB, 2 blocks/CU),
// depth-2 prefetch, one raw s_barrier per K-step, both-sides XOR swizzle,
// T1 XCD remap. Used for gemm1 (grid 2048).
// EPI: 1 = bias+relu->bf16
// ---------------------------------------------------------------------------
template <int EPI>
__global__ __launch_bounds__(512, 4)
void gemm_big_bf16(const u16* __restrict__ A, const u16* __restrict__ Bt,
                   const float* __restrict__ bias, void* __restrict__ Cout,
                   int M, int N, int K)
{
    __shared__ __align__(16) u16 As[3 * 8192];   // 3 x 16 KB (256 rows x 32)
    __shared__ __align__(16) u16 Bs[3 * 4096];   // 3 x  8 KB (128 rows x 32)

    const int tid = threadIdx.x;
    const int w = tid >> 6, l = tid & 63;
    const int wm = w >> 1, wn = w & 1;

    const int nbx   = N >> 7;
    const int nwg   = (M >> 8) * nbx;
    const int chunk = nwg >> 3;
    const int wg    = ((int)blockIdx.x & 7) * chunk + ((int)blockIdx.x >> 3);
    const long by   = wg / nbx;
    const long bx   = wg % nbx;

    const int lr  = l >> 2;                      // row within 16-row segment
    const int lsw = (l & 3) ^ ((l >> 3) & 3);    // swizzled source chunk
    const int lg  = l >> 4, lm = l & 15;         // frag k-group / row index
    const int sx  = (lm >> 1) & 3;               // read-side xor key

    const u16* Abase = A  + (size_t)(by * 256) * K;
    const u16* Bbase = Bt + (size_t)(bx * 128) * K;

    f32x4 acc[4][4] = {};

    auto stage = [&](int k0, int b) {
        u16* dA = As + b * 8192;
        u16* dB = Bs + b * 4096;
#pragma unroll
        for (int i = 0; i < 2; ++i) {
            const int seg = w * 2 + i;           // 0..15 -> 16 rows each
            GLD16(Abase + (size_t)(seg * 16 + lr) * K + k0 + lsw * 8,
                  dA + seg * 512);
        }
        GLD16(Bbase + (size_t)(w * 16 + lr) * K + k0 + lsw * 8,
              dB + w * 512);
    };

    const int NT = K >> 5;
    stage(0, 0);
    stage(32, 1);

    int cur = 0, pre = 2;
    for (int t = 0; t < NT; ++t) {
        if (t + 1 < NT) { WAITV3(); } else { WAITV0(); }
        BARRIER();
        if (t + 2 < NT) stage((t + 2) << 5, pre);

        const u16* as = As + cur * 8192;
        const u16* bs = Bs + cur * 4096;
        bf16x8 af[4], bfr[4];
#pragma unroll
        for (int m = 0; m < 4; ++m) {
            const int R = wm * 64 + m * 16 + lm;
            af[m] = *(const bf16x8*)&as[R * 32 + ((lg ^ sx) * 8)];
        }
#pragma unroll
        for (int n = 0; n < 4; ++n) {
            const int R = wn * 64 + n * 16 + lm;
            bfr[n] = *(const bf16x8*)&bs[R * 32 + ((lg ^ sx) * 8)];
        }
#pragma unroll
        for (int m = 0; m < 4; ++m)
#pragma unroll
            for (int n = 0; n < 4; ++n)
                acc[m][n] = __builtin_amdgcn_mfma_f32_16x16x32_bf16(
                    af[m], bfr[n], acc[m][n], 0, 0, 0);

        cur = (cur == 2) ? 0 : cur + 1;
        pre = (pre == 2) ? 0 : pre + 1;
    }

#pragma unroll
    for (int n = 0; n < 4; ++n) {
        const long col = bx * 128 + wn * 64 + n * 16 + lm;
        const float bb = bias[col];
#pragma unroll
        for (int m = 0; m < 4; ++m) {
#pragma unroll
            for (int j = 0; j < 4; ++j) {
                const long row = by * 256 + wm * 64 + m * 16 + lg * 4 + j;
                float e = acc[m][n][j] + bb;
                if (EPI == 1) e = fmaxf(e, 0.f);
                ((u16*)Cout)[row * (long)N + col] = f2bf(e);
            }
        }
    }
}

// ---------------------------------------------------------------------------
// SMALL-TILE core: BM=64, BN=128, BK=32, 256 threads = 4 waves (1M x 4N),
// wave tile 64x32 (acc[4][2]). LDS 3x(4+8)KB = 36KB -> 4 blocks/CU.
// r8/r9 sync skeleton. epi: 0 bias->bf16, 1 +relu->bf16, 2 +sigmoid->f32.
// ---------------------------------------------------------------------------
__device__ __forceinline__ void gemm64_core(
    const u16* __restrict__ A, const u16* __restrict__ Bt,
    const float* __restrict__ bias, void* __restrict__ Cout,
    int M, int N, int K, int epi, int bid,
    u16* __restrict__ As, u16* __restrict__ Bs)
{
    const int tid = threadIdx.x;
    const int w = tid >> 6, l = tid & 63;        // wave = col block (w*32)

    const int nbx   = N >> 7;
    const int nwg   = (M >> 6) * nbx;
    const int chunk = nwg >> 3;
    const int wg    = (bid & 7) * chunk + (bid >> 3);
    const long by   = wg / nbx;
    const long bx   = wg % nbx;

    const int lr  = l >> 2;
    const int lsw = (l & 3) ^ ((l >> 3) & 3);
    const int lg  = l >> 4, lm = l & 15;
    const int sx  = (lm >> 1) & 3;

    const u16* Abase = A  + (size_t)(by * 64) * K;
    const u16* Bbase = Bt + (size_t)(bx * 128) * K;

    f32x4 acc[4][2] = {};

    auto stage = [&](int k0, int b) {
        u16* dA = As + b * 2048;
        u16* dB = Bs + b * 4096;
        GLD16(Abase + (size_t)(w * 16 + lr) * K + k0 + lsw * 8, dA + w * 512);
#pragma unroll
        for (int i = 0; i < 2; ++i) {
            const int seg = w * 2 + i;
            GLD16(Bbase + (size_t)(seg * 16 + lr) * K + k0 + lsw * 8,
                  dB + seg * 512);
        }
    };

    const int NT = K >> 5;
    stage(0, 0);
    stage(32, 1);

    int cur = 0, pre = 2;
    for (int t = 0; t < NT; ++t) {
        if (t + 1 < NT) { WAITV3(); } else { WAITV0(); }
        BARRIER();
        if (t + 2 < NT) stage((t + 2) << 5, pre);

        const u16* as = As + cur * 2048;
        const u16* bs = Bs + cur * 4096;
        bf16x8 af[4], bfr[2];
#pragma unroll
        for (int m = 0; m < 4; ++m)
            af[m] = *(const bf16x8*)&as[(m * 16 + lm) * 32 + ((lg ^ sx) * 8)];
#pragma unroll
        for (int n = 0; n < 2; ++n) {
            const int R = w * 32 + n * 16 + lm;
            bfr[n] = *(const bf16x8*)&bs[R * 32 + ((lg ^ sx) * 8)];
        }
#pragma unroll
        for (int m = 0; m < 4; ++m)
#pragma unroll
            for (int n = 0; n < 2; ++n)
                acc[m][n] = __builtin_amdgcn_mfma_f32_16x16x32_bf16(
                    af[m], bfr[n], acc[m][n], 0, 0, 0);

        cur = (cur == 2) ? 0 : cur + 1;
        pre = (pre == 2) ? 0 : pre + 1;
    }

#pragma unroll
    for (int n = 0; n < 2; ++n) {
        const long col = bx * 128 + w * 32 + n * 16 + lm;
        const float bb = bias[col];
#pragma unroll
        for (int m = 0; m < 4; ++m) {
#pragma unroll
            for (int j = 0; j < 4; ++j) {
                const long row = by * 64 + m * 16 + lg * 4 + j;
                float e = acc[m][n][j] + bb;
                if (epi == 1) e = fmaxf(e, 0.f);
                if (epi == 2) {
                    e = 1.f / (1.f + expf(-e));
                    ((float*)Cout)[row * (long)N + col] = e;
                } else {
                    ((u16*)Cout)[row * (long)N + col] = f2bf(e);
                }
            }
        }
    }
}

// ---------------------------------------------------------------------------
// Fused: gemm2 (encoder z) + dec1 (per-code decoder hidden) — r14-proven.
// ---------------------------------------------------------------------------
__global__ __launch_bounds__(256, 4)
void gemm2_dec1_fused(const u16* __restrict__ h,  const u16* __restrict__ w2t,
                      const float* __restrict__ eb2, u16* __restrict__ z,
                      const u16* __restrict__ cb, const u16* __restrict__ wd1t,
                      const float* __restrict__ db1, u16* __restrict__ hcode)
{
    __shared__ __align__(16) u16 As[3 * 2048];
    __shared__ __align__(16) u16 Bs[3 * 4096];
    const int b = (int)blockIdx.x;
    if (b < 512)
        gemm64_core(h, w2t, eb2, z, B_, DL, DH, 0, b, As, Bs);
    else
        gemm64_core(cb, wd1t, db1, hcode, NE, DH, DL, 1, b - 512, As, Bs);
}

// ---------------------------------------------------------------------------
// dec2: Xcode = sigmoid(Hcode @ wd2t + db2) (f32), 1024 blocks.
// ---------------------------------------------------------------------------
__global__ __launch_bounds__(256, 4)
void gemm_dec2(const u16* __restrict__ hcode, const u16* __restrict__ wd2t,
               const float* __restrict__ db2, float* __restrict__ Xcode)
{
    __shared__ __align__(16) u16 As[3 * 2048];
    __shared__ __align__(16) u16 Bs[3 * 4096];
    gemm64_core(hcode, wd2t, db2, Xcode, NE, DIN, DH, 2, (int)blockIdx.x, As, Bs);
}

// ---------------------------------------------------------------------------
// VQ phase 1 v3: register-resident A, LDS-streamed codebook with the
// T4 counted-vmcnt pipeline (r8-proven skeleton): 32-code tiles, 3 LDS
// buffers (24KB), depth-2 prefetch, vmcnt(4) counted wait + one raw
// barrier per tile (replaces the per-tile __syncthreads full drain).
// cn2 for the eighth is staged into LDS in the prologue (1 GLD16/thread)
// so the loop's vmcnt FIFO contains ONLY the 4 stage loads per tile
// (cn2 reads are ds_read, lgkm-counted). Code-visit order is strictly
// ascending and every per-(row,code) MFMA chain is unchanged ->
// bitwise-identical val8/idx8 vs r14.
// Hazards (mirror gemm_big): reads of buf[t%3] gated by WAITV4+BARRIER
// at iter-t top (stage(t) is the oldest unretired group); stage(t+2)
// overwrites buf[(t-1)%3] whose readers all passed the iter-t barrier.
// ---------------------------------------------------------------------------
__global__ __launch_bounds__(256, 2)
void vq_score3(const u16* __restrict__ z, const u16* __restrict__ cbt,
               const float* __restrict__ cn2,
               float* __restrict__ val8, int* __restrict__ idx8)
{
    // [0,24576) u16: 3 x 8KB cb buffers; [24576,26624): cn2 (1024 f32);
    // prologue z staging transiently uses [0,32768).
    __shared__ __align__(16) u16 lds[32768];

    const int tid = threadIdx.x;
    const int w = tid >> 6, l = tid & 63;
    const int rq = blockIdx.x >> 3;
    const int q  = blockIdx.x & 7;

    const int st_row8 = tid >> 5;
    const int st_s    = (tid & 31) ^ st_row8;
    const int lg = l >> 4, lm = l & 15;
    const int swz_x = l & 7;

    // ---- prologue: stage z (two 64KB halves), load A-frags to registers ----
    bf16x8 af[4][8];
    const long zbase_row = (long)rq * 256;
#pragma unroll
    for (int h = 0; h < 2; ++h) {
#pragma unroll
        for (int i = 0; i < 16; ++i) {
            const int row = i * 8 + st_row8;
            const u16* g = z + (zbase_row + h * 128 + row) * DL + st_s * 8;
            GLD16(g, lds + ((size_t)i * 256 + w * 64) * 8);
        }
        __syncthreads();                       // drains vmcnt
        if ((w >> 1) == h) {
            const int lrow0 = (w & 1) * 64;
#pragma unroll
            for (int m = 0; m < 4; ++m) {
                const int lrow = lrow0 + m * 16 + lm;
#pragma unroll
                for (int kg = 0; kg < 8; ++kg) {
                    const int s = (kg * 4 + lg) ^ swz_x;
                    af[m][kg] = *(const bf16x8*)&lds[lrow * 256 + s * 8];
                }
            }
        }
        __syncthreads();                       // vmcnt == 0 after prologue
    }

    const int code00 = q * (NE / 8);
    const float* cn2s = (const float*)(lds + 24576);

    // stage this eighth's cn2 (1024 f32 = 4KB) — issued FIRST so the
    // t=0 WAITV4 retires it together with stage(0).
    GLD16(cn2 + code00 + (size_t)w * 256, lds + 24576 + w * 512);

    float bestv[16];
    int   besti[16];
#pragma unroll
    for (int k = 0; k < 16; ++k) { bestv[k] = 1e30f; besti[k] = 0; }

    auto stage_tile = [&](int t) {
        const int b = t % 3;
#pragma unroll
        for (int i = 0; i < 4; ++i) {
            const int c = i * 8 + st_row8;     // 0..31
            const u16* g = cbt + (size_t)(code00 + t * 32 + c) * DL + st_s * 8;
            GLD16(g, lds + (size_t)b * 8192 + ((size_t)i * 256 + w * 64) * 8);
        }
    };

    stage_tile(0);
    stage_tile(1);

    for (int t = 0; t < 32; ++t) {
        if (t + 1 < 32) { WAITV4(); } else { WAITV0(); }
        BARRIER();
        if (t + 2 < 32) stage_tile(t + 2);

        const u16* buf = lds + (size_t)(t % 3) * 8192;
#pragma unroll
        for (int n = 0; n < 2; ++n) {
            const int code_g = code00 + t * 32 + n * 16 + lm;
            const float cn2v = cn2s[t * 32 + n * 16 + lm];
            bf16x8 bfr[8];
#pragma unroll
            for (int kg = 0; kg < 8; ++kg) {
                const int lrow = n * 16 + lm;
                const int s = (kg * 4 + lg) ^ swz_x;
                bfr[kg] = *(const bf16x8*)&buf[lrow * 256 + s * 8];
            }
            f32x4 acc[4] = {};
#pragma unroll
            for (int kg = 0; kg < 8; ++kg)
#pragma unroll
                for (int m = 0; m < 4; ++m)
                    acc[m] = __builtin_amdgcn_mfma_f32_16x16x32_bf16(
                        af[m][kg], bfr[kg], acc[m], 0, 0, 0);
#pragma unroll
            for (int m = 0; m < 4; ++m)
#pragma unroll
                for (int j = 0; j < 4; ++j) {
                    const float s = cn2v - acc[m][j];
                    const int k16 = m * 4 + j;
                    if (s < bestv[k16]) { bestv[k16] = s; besti[k16] = code_g; }
                }
        }
    }

    // lane-reduce across the 16 code-lanes (tie-break lowest idx)
#pragma unroll
    for (int off = 1; off < 16; off <<= 1) {
#pragma unroll
        for (int k = 0; k < 16; ++k) {
            const float ov = __shfl_xor(bestv[k], off);
            const int   oi = __shfl_xor(besti[k], off);
            if (ov < bestv[k] || (ov == bestv[k] && oi < besti[k])) {
                bestv[k] = ov; besti[k] = oi;
            }
        }
    }
    if (lm == 0) {
#pragma unroll
        for (int m = 0; m < 4; ++m)
#pragma unroll
            for (int j = 0; j < 4; ++j) {
                const long row = zbase_row + w * 64 + m * 16 + lg * 4 + j;
                val8[(size_t)q * B_ + row] = bestv[m * 4 + j];
                idx8[(size_t)q * B_ + row] = besti[m * 4 + j];
            }
    }
}

// ---------------------------------------------------------------------------
// VQ phase 2: per row pick best of 8 candidates (tie-break lowest idx),
// write final index, accumulate loss partial.
// ---------------------------------------------------------------------------
__global__ __launch_bounds__(256)
void vq_select2(const float* __restrict__ val8, const int* __restrict__ idx8,
                const u16* __restrict__ z, const float* __restrict__ cb,
                int* __restrict__ idxf, float* __restrict__ partial)
{
    __shared__ int   s_idx[256];
    __shared__ float s_red[4];
    const int tid = threadIdx.x;
    const long row = (long)blockIdx.x * 256 + tid;

    float bv = val8[row];
    int   bi = idx8[row];
#pragma unroll
    for (int qq = 1; qq < 8; ++qq) {
        const float v = val8[(size_t)qq * B_ + row];
        const int   i = idx8[(size_t)qq * B_ + row];
        if (v < bv || (v == bv && i < bi)) { bv = v; bi = i; }
    }
    s_idx[tid] = bi;
    idxf[row]  = bi;
    __syncthreads();

    float ls = 0.f;
    const int sub = tid & 7;
#pragma unroll
    for (int pass = 0; pass < 8; ++pass) {
        const int rl = pass * 32 + (tid >> 3);
        const int gi = s_idx[rl];
        const long rg = (long)blockIdx.x * 256 + rl;
#pragma unroll
        for (int tt = 0; tt < 8; ++tt) {
            const int d = sub * 4 + tt * 32;
            float4 c4 = *(const float4*)(cb + (long)gi * DL + d);
            ushort4 zu = *(const ushort4*)(z + rg * DL + d);
            const float dx = c4.x - bf2f(zu.x), dy = c4.y - bf2f(zu.y);
            const float dz = c4.z - bf2f(zu.z), dw = c4.w - bf2f(zu.w);
            ls += dx * dx + dy * dy + dz * dz + dw * dw;
        }
    }
#pragma unroll
    for (int off = 32; off; off >>= 1) ls += __shfl_down(ls, off);
    if ((tid & 63) == 0) s_red[tid >> 6] = ls;
    __syncthreads();
    if (tid == 0)
        partial[blockIdx.x] = s_red[0] + s_red[1] + s_red[2] + s_red[3];
}

// ---------------------------------------------------------------------------
// gather + loss: blocks [0,4096) gather out[row] = Xcode[idxf[row]];
// block 4096 computes loss = 1.25 * sum(partial[64]) / (B_*DL).
// ---------------------------------------------------------------------------
__global__ __launch_bounds__(256)
void gather_loss(const float* __restrict__ Xcode, const int* __restrict__ idxf,
                 const float* __restrict__ partial, float* __restrict__ out,
                 float* __restrict__ loss_out)
{
    const int tid = threadIdx.x;
    if (blockIdx.x == 4096) {
        __shared__ float s_red[4];
        float s = (tid < 64) ? partial[tid] : 0.f;
#pragma unroll
        for (int off = 32; off; off >>= 1) s += __shfl_down(s, off);
        if ((tid & 63) == 0) s_red[tid >> 6] = s;
        __syncthreads();
        if (tid == 0)
            loss_out[0] = 1.25f * (s_red[0] + s_red[1] + s_red[2] + s_red[3])
                          / (float)((long)B_ * DL);
        return;
    }
    const int lane = tid & 63;
    const long row = (long)blockIdx.x * 4 + (tid >> 6);
    const long gi  = idxf[row];
    const float* src = Xcode + gi * DIN;
    float*       dst = out + row * DIN;
#pragma unroll
    for (int t = 0; t < 4; ++t) {
        const int d = lane * 4 + t * 256;
        *(float4*)(dst + d) = *(const float4*)(src + d);
    }
}

// ---------------------------------------------------------------------------
extern "C" void kernel_launch(void* const* d_in, const int* in_sizes, int n_in,
                              void* d_out, int out_size, void* d_ws, size_t ws_size,
                              hipStream_t stream)
{
    const float* x   = (const float*)d_in[0];
    const float* ew1 = (const float*)d_in[1];
    const float* eb1 = (const float*)d_in[2];
    const float* ew2 = (const float*)d_in[3];
    const float* eb2 = (const float*)d_in[4];
    const float* cbk = (const float*)d_in[5];
    const float* dw1 = (const float*)d_in[6];
    const float* db1 = (const float*)d_in[7];
    const float* dw2 = (const float*)d_in[8];
    const float* db2 = (const float*)d_in[9];
    float* out = (float*)d_out;

    char* p = (char*)d_ws;
    auto alloc = [&](size_t bytes) {
        char* r = p; p += (bytes + 255) & ~(size_t)255; return r;
    };
    u16*   x_bf  = (u16*)alloc((size_t)B_ * DIN * 2);  // x; later Hcode [NE,DH]
    u16*   h_bf  = (u16*)alloc((size_t)B_ * DH * 2);   // encoder h
    u16*   z_bf  = (u16*)alloc((size_t)B_ * DL * 2);
    u16*   cb_bf = (u16*)alloc((size_t)NE * DL * 2);
    u16*   w1t   = (u16*)alloc((size_t)DH * DIN * 2);  // [N][K] bf16
    u16*   w2t   = (u16*)alloc((size_t)DL * DH * 2);
    u16*   wd1t  = (u16*)alloc((size_t)DH * DL * 2);
    u16*   wd2t  = (u16*)alloc((size_t)DIN * DH * 2);
    float* Xcode = (float*)alloc((size_t)NE * DIN * 4);   // per-code recon
    float* cn2   = (float*)alloc((size_t)NE * 4);
    float* val8  = (float*)alloc((size_t)8 * B_ * 4);
    int*   idx8  = (int*)alloc((size_t)8 * B_ * 4);
    int*   idxf  = (int*)alloc((size_t)B_ * 4);
    float* part  = (float*)alloc(64 * 4);

    u16* hcode = x_bf;   // [NE, DH] bf16 = 32 MiB overlay; x_bf dead after gemm1

    // fused prologue: casts, weight transposes, cn2 (one launch)
    prep_fused<<<25600, 256, 0, stream>>>(x, x_bf, cbk, cb_bf,
                                          ew1, w1t, ew2, w2t,
                                          dw1, wd1t, dw2, wd2t, cn2);

    // encoder GEMM1 (reads x_bf -- last reader before hcode overlay)
    gemm_big_bf16<1><<<(B_ / 256) * (DH / 128), 512, 0, stream>>>(
        x_bf, w1t, eb1, h_bf, B_, DH, DIN);

    // fused: encoder GEMM2 (512 blocks) + decoder dec1 (2048 blocks)
    gemm2_dec1_fused<<<2560, 256, 0, stream>>>(h_bf, w2t, eb2, z_bf,
                                               cb_bf, wd1t, db1, hcode);

    // decoder dec2 (per-code recon), independent of VQ chain below
    gemm_dec2<<<(NE / 64) * (DIN / 128), 256, 0, stream>>>(
        hcode, wd2t, db2, Xcode);

    // vector quantizer -> final index per row + loss partials
    vq_score3<<<512, 256, 0, stream>>>(z_bf, cb_bf, cn2, val8, idx8);
    vq_select2<<<B_ / 256, 256, 0, stream>>>(val8, idx8, z_bf, cbk, idxf, part);

    // final gather + loss (one launch)
    gather_loss<<<4097, 256, 0, stream>>>(Xcode, idxf, part, out,
                                          out + (size_t)B_ * DIN);
}